// Round 10
// baseline (1088.240 us; speedup 1.0000x reference)
//
#include <hip/hip_runtime.h>
#include <hip/hip_bf16.h>

// LlamaAttentionWithLora on MI355X — round 10.
// Launch-graph collapse: 13 -> 6 kernels. prep1 = rope_table + hs_prep + 4 weight
// transposes (wo gets its own woT region, runs pre-QKV) + wb_build. post1 = rope16 +
// transpose_v. attn = prefill + decode merged. GEMMs identical to round 9.

#define H_    4096
#define NH_   32
#define HD_   128
#define T_    2592
#define DOFF_ 2560
#define DEC_  32
#define LMAX_ 512
#define RANK_ 16
#define MPAD_ 2816

__constant__ float SCALE_ = 0.08838834764831845f; // 128^-0.5

typedef __bf16 bf16x8 __attribute__((ext_vector_type(8)));
typedef __bf16 bf16x4 __attribute__((ext_vector_type(4)));
typedef float  f32x4  __attribute__((ext_vector_type(4)));

__device__ __forceinline__ void async_cp16(const __bf16* g, __bf16* l) {
    __builtin_amdgcn_global_load_lds(
        (const __attribute__((address_space(1))) void*)g,
        (__attribute__((address_space(3))) void*)l, 16, 0, 0);
}

// ---------------------------------------------------------------- prep1: fused pre-GEMM work
// blocks [0,2592): hs_prep | [2592,18976): 4x weight transpose | [18976,19040): wb_build
// | [19040,19296): rope tables
__global__ __launch_bounds__(256)
void prep1_kernel(const float* __restrict__ X, __bf16* __restrict__ Xb,
                  const float* __restrict__ la0, const float* __restrict__ la1,
                  const float* __restrict__ la2, __bf16* __restrict__ TMP16,
                  const float* __restrict__ wq, const float* __restrict__ wk,
                  const float* __restrict__ wv, const float* __restrict__ wo,
                  __bf16* __restrict__ wT, __bf16* __restrict__ woT,
                  const float* __restrict__ lbq, const float* __restrict__ lbk,
                  const float* __restrict__ lbv, const float* __restrict__ lbo,
                  __bf16* __restrict__ WB16, __bf16* __restrict__ WBo16,
                  float* __restrict__ cost, float* __restrict__ sint)
{
    const int bid = blockIdx.x;
    const int tid = threadIdx.x;

    if (bid < T_) {
        // ------------------------------------------------ hs_prep
        const int r = bid;
        const float* xr = X + (size_t)r * H_;
        __bf16* br = Xb + (size_t)r * H_;
        #pragma unroll
        for (int i = 0; i < 4; ++i) {
            float4 v = ((const float4*)xr)[tid + i * 256];
            bf16x4 w; w[0] = (__bf16)v.x; w[1] = (__bf16)v.y; w[2] = (__bf16)v.z; w[3] = (__bf16)v.w;
            ((bf16x4*)br)[tid + i * 256] = w;
        }
        const int si = (r < 648) ? 0 : (r < 1296 ? 1 : (r < 1944 ? 2 : 3));
        const int c    = tid & 15;
        const int part = tid >> 4;
        const float* wa0 = la0 + (size_t)si * H_ * RANK_;
        const float* wa1 = la1 + (size_t)si * H_ * RANK_;
        const float* wa2 = la2 + (size_t)si * H_ * RANK_;
        float s0 = 0.f, s1 = 0.f, s2 = 0.f;
        const int h0 = part * 256;
        for (int h = h0; h < h0 + 256; ++h) {
            const float xv = xr[h];
            s0 += xv * wa0[(size_t)h * RANK_ + c];
            s1 += xv * wa1[(size_t)h * RANK_ + c];
            s2 += xv * wa2[(size_t)h * RANK_ + c];
        }
        __shared__ float red[3][16][17];
        red[0][part][c] = s0; red[1][part][c] = s1; red[2][part][c] = s2;
        __syncthreads();
        if (tid < 192) {
            const int z = tid >> 6, cc = tid & 63;
            float t = 0.f;
            if ((cc >> 4) == si) {
                #pragma unroll
                for (int p = 0; p < 16; ++p) t += red[z][p][cc & 15];
            }
            TMP16[((size_t)z * MPAD_ + r) * 64 + cc] = (__bf16)t;
        }
    } else if (bid < T_ + 16384) {
        // ------------------------------------------------ weight transpose (64x64 tiles)
        const int t = bid - T_;
        const int z = t >> 12;
        const int rem = t & 4095;
        const int bx = (rem >> 6) * 64;
        const int by = (rem & 63) * 64;
        const float* W = (z == 0) ? wq : (z == 1 ? wk : (z == 2 ? wv : wo));
        __bf16* To = (z < 3) ? wT + (size_t)z * H_ * H_ : woT;
        __shared__ float s[64][65];
        #pragma unroll
        for (int i = 0; i < 4; ++i) {
            const int idx = i * 256 + tid;
            const int r  = idx >> 4;
            const int c4 = (idx & 15) * 4;
            float4 v = *(const float4*)&W[(size_t)(by + r) * H_ + bx + c4];
            s[r][c4] = v.x; s[r][c4 + 1] = v.y; s[r][c4 + 2] = v.z; s[r][c4 + 3] = v.w;
        }
        __syncthreads();
        #pragma unroll
        for (int i = 0; i < 2; ++i) {
            const int idx = i * 256 + tid;
            const int n  = idx >> 3;
            const int kc = (idx & 7) * 8;
            bf16x8 w;
            #pragma unroll
            for (int j = 0; j < 8; ++j) w[j] = (__bf16)s[kc + j][n];
            *(bf16x8*)&To[(size_t)(bx + n) * H_ + by + kc] = w;
        }
    } else if (bid < T_ + 16384 + 64) {
        // ------------------------------------------------ wb_build (64 blocks: z = t>>4, 256-col chunk = t&15)
        const int t = bid - (T_ + 16384);
        const int z = t >> 4;
        const int n = (t & 15) * 256 + tid;
        const float* lb = (z == 0) ? lbq : (z == 1 ? lbk : (z == 2 ? lbv : lbo));
        __bf16* dst = (z < 3) ? WB16 + ((size_t)z * H_ + n) * 64 : WBo16 + (size_t)n * 64;
        __bf16 row[64];
        #pragma unroll
        for (int si = 0; si < 4; ++si)
            #pragma unroll
            for (int c = 0; c < 16; ++c)
                row[si * 16 + c] = (__bf16)lb[((size_t)si * 16 + c) * H_ + n];
        #pragma unroll
        for (int i = 0; i < 8; ++i) *(bf16x8*)&dst[i * 8] = *(const bf16x8*)&row[i * 8];
    } else {
        // ------------------------------------------------ rope tables (256 blocks x 4 positions)
        const int t = bid - (T_ + 16384 + 64);
        const int p = t * 4 + (tid >> 6);
        const int i = tid & 63;
        const float inv = powf(10000.f, -(float)(2 * i) / (float)HD_);
        const float a = (float)p * inv;
        cost[p * 64 + i] = cosf(a);
        sint[p * 64 + i] = sinf(a);
    }
}

// ---------------------------------------------------------------- QKV GEMM (128x256, BK=64, 3-buf ring) + fused lora, bf16 out
__global__ __launch_bounds__(512, 2)
void gemm_qkv(const __bf16* __restrict__ A, const __bf16* __restrict__ Bt,
              const __bf16* __restrict__ TMP16, const __bf16* __restrict__ WB16,
              __bf16* __restrict__ O0, __bf16* __restrict__ O1, __bf16* __restrict__ O2, int M)
{
    const int hw = blockIdx.y * 21 + blockIdx.x;
    const int work = (hw & 7) * 126 + (hw >> 3);     // 1008 = 8 * 126
    const int bm0 = (work % 21) * 128;
    const int bn0 = (work / 21) * 256;

    __shared__ __align__(16) __bf16 Asl[3][128 * 64];
    __shared__ __align__(16) __bf16 Bsl[3][256 * 64];

    const int tid = threadIdx.x, lane = tid & 63, wid = tid >> 6;
    const int wr = wid >> 2, wc = wid & 3;
    const int fr = lane & 15, fq = lane >> 4;

    int arow[2], aoff[2], brow[4], boff[4];
    #pragma unroll
    for (int i = 0; i < 2; ++i) {
        const int ci = i * 512 + tid;
        arow[i] = ci >> 3;
        aoff[i] = ((ci & 7) ^ (arow[i] & 7)) * 8;
    }
    #pragma unroll
    for (int i = 0; i < 4; ++i) {
        const int ci = i * 512 + tid;
        brow[i] = ci >> 3;
        boff[i] = ((ci & 7) ^ (brow[i] & 7)) * 8;
    }
    const __bf16* Ab = A  + (size_t)bm0 * H_;
    const __bf16* Bb = Bt + (size_t)bn0 * H_;

    auto stageA = [&](int buf, int kt2) {
        const int kb = kt2 * 64;
        #pragma unroll
        for (int i = 0; i < 2; ++i)
            async_cp16(Ab + (size_t)arow[i] * H_ + kb + aoff[i],
                       &Asl[buf][(i * 512 + wid * 64) * 8]);
    };
    auto stageB1 = [&](int buf, int kt2) {
        async_cp16(Bb + (size_t)brow[0] * H_ + kt2 * 64 + boff[0],
                   &Bsl[buf][(wid * 64) * 8]);
    };
    auto stageB3 = [&](int buf, int kt2) {
        const int kb = kt2 * 64;
        #pragma unroll
        for (int i = 1; i < 4; ++i)
            async_cp16(Bb + (size_t)brow[i] * H_ + kb + boff[i],
                       &Bsl[buf][(i * 512 + wid * 64) * 8]);
    };
    auto rdA = [&](int buf, int kh, int mi) -> bf16x8 {
        const int row = wr * 64 + mi * 16 + fr;
        const int pc  = (kh * 4 + fq) ^ (row & 7);
        return *(const bf16x8*)&Asl[buf][row * 64 + pc * 8];
    };
    auto rdB = [&](int buf, int kh, int nj) -> bf16x8 {
        const int row = wc * 64 + nj * 16 + fr;
        const int pc  = (kh * 4 + fq) ^ (row & 7);
        return *(const bf16x8*)&Bsl[buf][row * 64 + pc * 8];
    };

    f32x4 acc[4][4] = {};

    stageA(0, 0); stageB1(0, 0); stageB3(0, 0);
    stageA(1, 1); stageB1(1, 1); stageB3(1, 1);
    asm volatile("s_waitcnt vmcnt(6)");
    __builtin_amdgcn_sched_barrier(0);
    __builtin_amdgcn_s_barrier();

    const int NT = H_ / 64;
    int cur = 0, nxt = 2;
    for (int kt = 0; kt < NT; ++kt) {
        const bool pf = (kt + 2 < NT);
        bf16x8 af[4], bfr[4];

        #pragma unroll
        for (int mi = 0; mi < 4; ++mi) af[mi] = rdA(cur, 0, mi);
        #pragma unroll
        for (int nj = 0; nj < 4; ++nj) bfr[nj] = rdB(cur, 0, nj);
        if (pf) { stageA(nxt, kt + 2); stageB1(nxt, kt + 2); }
        __builtin_amdgcn_s_barrier();
        asm volatile("s_waitcnt lgkmcnt(0)");
        __builtin_amdgcn_sched_barrier(0);
        __builtin_amdgcn_s_setprio(1);
        #pragma unroll
        for (int mi = 0; mi < 4; ++mi)
            #pragma unroll
            for (int nj = 0; nj < 4; ++nj)
                acc[mi][nj] = __builtin_amdgcn_mfma_f32_16x16x32_bf16(af[mi], bfr[nj], acc[mi][nj], 0, 0, 0);
        __builtin_amdgcn_s_setprio(0);
        __builtin_amdgcn_s_barrier();

        #pragma unroll
        for (int mi = 0; mi < 4; ++mi) af[mi] = rdA(cur, 1, mi);
        #pragma unroll
        for (int nj = 0; nj < 4; ++nj) bfr[nj] = rdB(cur, 1, nj);
        if (pf) stageB3(nxt, kt + 2);
        __builtin_amdgcn_s_barrier();
        asm volatile("s_waitcnt lgkmcnt(0)");
        __builtin_amdgcn_sched_barrier(0);
        __builtin_amdgcn_s_setprio(1);
        #pragma unroll
        for (int mi = 0; mi < 4; ++mi)
            #pragma unroll
            for (int nj = 0; nj < 4; ++nj)
                acc[mi][nj] = __builtin_amdgcn_mfma_f32_16x16x32_bf16(af[mi], bfr[nj], acc[mi][nj], 0, 0, 0);
        __builtin_amdgcn_s_setprio(0);
        if (pf)               asm volatile("s_waitcnt vmcnt(6)");
        else if (kt + 1 < NT) asm volatile("s_waitcnt vmcnt(0)");
        __builtin_amdgcn_sched_barrier(0);
        __builtin_amdgcn_s_barrier();

        cur = (cur == 2) ? 0 : cur + 1;
        nxt = (nxt == 2) ? 0 : nxt + 1;
    }

    const int colbase = bn0 + wc * 64;
    const int mat = colbase >> 12;
    __bf16* O = (mat == 0) ? O0 : (mat == 1 ? O1 : O2);
    const __bf16* TPm = TMP16 + (size_t)mat * MPAD_ * 64;
    bf16x8 aT[4][2], bW[4][2];
    #pragma unroll
    for (int mi = 0; mi < 4; ++mi)
        #pragma unroll
        for (int kh = 0; kh < 2; ++kh)
            aT[mi][kh] = *(const bf16x8*)&TPm[(size_t)(bm0 + wr * 64 + mi * 16 + fr) * 64 + kh * 32 + fq * 8];
    #pragma unroll
    for (int nj = 0; nj < 4; ++nj)
        #pragma unroll
        for (int kh = 0; kh < 2; ++kh)
            bW[nj][kh] = *(const bf16x8*)&WB16[(size_t)(colbase + nj * 16 + fr) * 64 + kh * 32 + fq * 8];
    #pragma unroll
    for (int mi = 0; mi < 4; ++mi)
        #pragma unroll
        for (int nj = 0; nj < 4; ++nj) {
            acc[mi][nj] = __builtin_amdgcn_mfma_f32_16x16x32_bf16(aT[mi][0], bW[nj][0], acc[mi][nj], 0, 0, 0);
            acc[mi][nj] = __builtin_amdgcn_mfma_f32_16x16x32_bf16(aT[mi][1], bW[nj][1], acc[mi][nj], 0, 0, 0);
        }
    #pragma unroll
    for (int mi = 0; mi < 4; ++mi)
        #pragma unroll
        for (int nj = 0; nj < 4; ++nj) {
            const int cc = (colbase + nj * 16 + fr) & 4095;
            #pragma unroll
            for (int rr = 0; rr < 4; ++rr) {
                const int row = bm0 + wr * 64 + mi * 16 + fq * 4 + rr;
                if (row < M) O[(size_t)row * H_ + cc] = (__bf16)acc[mi][nj][rr];
            }
        }
}

// ---------------------------------------------------------------- O-proj GEMM (256x192, BK=64) + fused lora, f32 out
__global__ __launch_bounds__(512, 2)
void gemm_out(const __bf16* __restrict__ A, const __bf16* __restrict__ Bt,
              const __bf16* __restrict__ TMPo16, const __bf16* __restrict__ WBo16,
              float* __restrict__ C, int M, int Ntot)
{
    const int NY = gridDim.y;
    const int total = gridDim.x * NY;
    const int bid = blockIdx.x * NY + blockIdx.y;
    const int q = total >> 3, r8 = total & 7;
    const int xcd = bid & 7, j = bid >> 3;
    const int swz = (xcd < r8 ? xcd * (q + 1) : r8 * (q + 1) + (xcd - r8) * q) + j;
    const int bm0 = (swz / NY) * 256;
    const int bn0 = (swz % NY) * 192;

    __shared__ __align__(16) __bf16 Asl[2][256 * 64];
    __shared__ __align__(16) __bf16 Bsl[2][192 * 64];

    const int tid = threadIdx.x, lane = tid & 63, wid = tid >> 6;
    const int wr = wid >> 2, wc = wid & 3;
    const int fr = lane & 15, fq = lane >> 4;

    int arow[4], aoff[4], brow[3], boff[3];
    #pragma unroll
    for (int i = 0; i < 4; ++i) {
        const int ci = i * 512 + tid;
        arow[i] = ci >> 3;
        aoff[i] = ((ci & 7) ^ (arow[i] & 7)) * 8;
    }
    #pragma unroll
    for (int i = 0; i < 3; ++i) {
        const int ci = i * 512 + tid;
        brow[i] = ci >> 3;
        boff[i] = ((ci & 7) ^ (brow[i] & 7)) * 8;
    }
    const __bf16* Ab = A  + (size_t)bm0 * H_;
    const __bf16* Bb = Bt + (size_t)bn0 * H_;

    auto stage = [&](int buf, int kt1) {
        const int kb = kt1 * 64;
        #pragma unroll
        for (int i = 0; i < 4; ++i)
            async_cp16(Ab + (size_t)arow[i] * H_ + kb + aoff[i],
                       &Asl[buf][(i * 512 + wid * 64) * 8]);
        #pragma unroll
        for (int i = 0; i < 3; ++i)
            async_cp16(Bb + (size_t)brow[i] * H_ + kb + boff[i],
                       &Bsl[buf][(i * 512 + wid * 64) * 8]);
    };
    auto rdA = [&](int buf, int kh, int mi) -> bf16x8 {
        const int row = wr * 128 + mi * 16 + fr;
        const int kc  = kh * 4 + fq;
        return *(const bf16x8*)&Asl[buf][row * 64 + ((kc ^ (row & 7)) << 3)];
    };
    auto rdB = [&](int buf, int kh, int nj) -> bf16x8 {
        const int row = wc * 48 + nj * 16 + fr;
        const int kc  = kh * 4 + fq;
        return *(const bf16x8*)&Bsl[buf][row * 64 + ((kc ^ (row & 7)) << 3)];
    };

    f32x4 acc[8][3] = {};

    stage(0, 0);
    asm volatile("s_waitcnt vmcnt(0)");
    __builtin_amdgcn_sched_barrier(0);
    __builtin_amdgcn_s_barrier();

    const int NT = H_ / 64;
    for (int kt = 0; kt < NT; ++kt) {
        const int cur = kt & 1, nb = cur ^ 1;
        const bool pf = (kt + 1 < NT);
        bf16x8 af[8], bfr[3];

        #pragma unroll
        for (int mi = 0; mi < 8; ++mi) af[mi] = rdA(cur, 0, mi);
        #pragma unroll
        for (int nj = 0; nj < 3; ++nj) bfr[nj] = rdB(cur, 0, nj);
        if (pf) stage(nb, kt + 1);
        __builtin_amdgcn_s_barrier();
        asm volatile("s_waitcnt lgkmcnt(0)");
        __builtin_amdgcn_sched_barrier(0);
        __builtin_amdgcn_s_setprio(1);
        #pragma unroll
        for (int mi = 0; mi < 8; ++mi)
            #pragma unroll
            for (int nj = 0; nj < 3; ++nj)
                acc[mi][nj] = __builtin_amdgcn_mfma_f32_16x16x32_bf16(af[mi], bfr[nj], acc[mi][nj], 0, 0, 0);
        __builtin_amdgcn_s_setprio(0);
        __builtin_amdgcn_s_barrier();

        #pragma unroll
        for (int mi = 0; mi < 8; ++mi) af[mi] = rdA(cur, 1, mi);
        #pragma unroll
        for (int nj = 0; nj < 3; ++nj) bfr[nj] = rdB(cur, 1, nj);
        __builtin_amdgcn_s_barrier();
        asm volatile("s_waitcnt lgkmcnt(0)");
        __builtin_amdgcn_sched_barrier(0);
        __builtin_amdgcn_s_setprio(1);
        #pragma unroll
        for (int mi = 0; mi < 8; ++mi)
            #pragma unroll
            for (int nj = 0; nj < 3; ++nj)
                acc[mi][nj] = __builtin_amdgcn_mfma_f32_16x16x32_bf16(af[mi], bfr[nj], acc[mi][nj], 0, 0, 0);
        __builtin_amdgcn_s_setprio(0);
        asm volatile("s_waitcnt vmcnt(0)");
        __builtin_amdgcn_sched_barrier(0);
        __builtin_amdgcn_s_barrier();
    }

    const int colw = bn0 + wc * 48;
    bf16x8 aT[8][2], bW[3][2];
    #pragma unroll
    for (int mi = 0; mi < 8; ++mi)
        #pragma unroll
        for (int kh = 0; kh < 2; ++kh)
            aT[mi][kh] = *(const bf16x8*)&TMPo16[(size_t)(bm0 + wr * 128 + mi * 16 + fr) * 64 + kh * 32 + fq * 8];
    #pragma unroll
    for (int nj = 0; nj < 3; ++nj)
        #pragma unroll
        for (int kh = 0; kh < 2; ++kh)
            bW[nj][kh] = *(const bf16x8*)&WBo16[(size_t)(colw + nj * 16 + fr) * 64 + kh * 32 + fq * 8];
    #pragma unroll
    for (int mi = 0; mi < 8; ++mi)
        #pragma unroll
        for (int nj = 0; nj < 3; ++nj) {
            acc[mi][nj] = __builtin_amdgcn_mfma_f32_16x16x32_bf16(aT[mi][0], bW[nj][0], acc[mi][nj], 0, 0, 0);
            acc[mi][nj] = __builtin_amdgcn_mfma_f32_16x16x32_bf16(aT[mi][1], bW[nj][1], acc[mi][nj], 0, 0, 0);
        }
    #pragma unroll
    for (int mi = 0; mi < 8; ++mi)
        #pragma unroll
        for (int nj = 0; nj < 3; ++nj) {
            const int col = colw + nj * 16 + fr;
            if (col < Ntot) {
                #pragma unroll
                for (int rr = 0; rr < 4; ++rr) {
                    const int row = bm0 + wr * 128 + mi * 16 + fq * 4 + rr;
                    if (row < M) C[(size_t)row * H_ + col] = acc[mi][nj][rr];
                }
            }
        }
}

// ---------------------------------------------------------------- LoRA stage 1 (bf16 X) -> TMPo16[r][64]
__global__ __launch_bounds__(256)
void lora_tmp_bf16_kernel(const __bf16* __restrict__ X,
                          const float* __restrict__ la, __bf16* __restrict__ TMPo16)
{
    const int r = blockIdx.x;
    const int si = (r < 648) ? 0 : (r < 1296 ? 1 : (r < 1944 ? 2 : 3));
    const float* wa = la + (size_t)si * H_ * RANK_;
    const int c    = threadIdx.x & 15;
    const int part = threadIdx.x >> 4;
    const __bf16* xr = X + (size_t)r * H_;
    float s = 0.f;
    const int h0 = part * 256;
    for (int h = h0; h < h0 + 256; ++h) s += (float)xr[h] * wa[(size_t)h * RANK_ + c];
    __shared__ float red[16][17];
    red[part][c] = s;
    __syncthreads();
    if (threadIdx.x < 64) {
        const int cc = threadIdx.x;
        float t = 0.f;
        if ((cc >> 4) == si) {
            #pragma unroll
            for (int p = 0; p < 16; ++p) t += red[p][cc & 15];
        }
        TMPo16[(size_t)r * 64 + cc] = (__bf16)t;
    }
}

// ---------------------------------------------------------------- post1: rope16 + transpose_v fused
__global__ __launch_bounds__(256)
void post1_kernel(__bf16* __restrict__ q16, __bf16* __restrict__ k16,
                  const __bf16* __restrict__ v16, __bf16* __restrict__ vT,
                  const int* __restrict__ kv_lens,
                  const float* __restrict__ cost, const float* __restrict__ sint)
{
    const int bid = blockIdx.x;
    const int tid = threadIdx.x;

    if (bid < T_) {
        // ------------------------------------------------ rope16
        const int r = bid;
        int pos; bool dok;
        if (r < DOFF_) {
            if      (r < 1024) pos = r;
            else if (r < 1536) pos = r - 1024;
            else if (r < 2304) pos = r - 1536;
            else               pos = r - 2304;
            dok = true;
        } else {
            pos = kv_lens[r - DOFF_];
            dok = false;
        }
        const int h = tid >> 3, sub = tid & 7;
        const int i0 = sub * 8;
        const size_t b1 = (size_t)r * H_ + h * HD_ + i0;
        const size_t b2 = b1 + 64;

        float cs[8], sn[8];
        #pragma unroll
        for (int j = 0; j < 8; ++j) { cs[j] = cost[pos * 64 + i0 + j]; sn[j] = sint[pos * 64 + i0 + j]; }

        {
            bf16x8 x1 = *(const bf16x8*)&q16[b1], x2 = *(const bf16x8*)&q16[b2];
            bf16x8 o1, o2;
            #pragma unroll
            for (int j = 0; j < 8; ++j) {
                const float f1 = (float)x1[j], f2 = (float)x2[j];
                o1[j] = (__bf16)(f1 * cs[j] - f2 * sn[j]);
                o2[j] = (__bf16)(f2 * cs[j] + f1 * sn[j]);
            }
            *(bf16x8*)&q16[b1] = o1; *(bf16x8*)&q16[b2] = o2;
        }
        if (dok) {
            bf16x8 x1 = *(const bf16x8*)&k16[b1], x2 = *(const bf16x8*)&k16[b2];
            bf16x8 o1, o2;
            #pragma unroll
            for (int j = 0; j < 8; ++j) {
                const float f1 = (float)x1[j], f2 = (float)x2[j];
                o1[j] = (__bf16)(f1 * cs[j] - f2 * sn[j]);
                o2[j] = (__bf16)(f2 * cs[j] + f1 * sn[j]);
            }
            *(bf16x8*)&k16[b1] = o1; *(bf16x8*)&k16[b2] = o2;
        }
    } else {
        // ------------------------------------------------ transpose_v (1280 blocks)
        const int t = bid - T_;
        const int tb = t % 40;
        const int h  = t / 40;
        __shared__ __bf16 s[64][136];
        #pragma unroll
        for (int i = 0; i < 4; ++i) {
            const int idx = i * 256 + tid;
            const int row = idx >> 4;
            const int c8  = (idx & 15) * 8;
            *(bf16x8*)&s[row][c8] = *(const bf16x8*)&v16[(size_t)(tb * 64 + row) * H_ + h * HD_ + c8];
        }
        __syncthreads();
        #pragma unroll
        for (int i = 0; i < 4; ++i) {
            const int idx = i * 256 + tid;
            const int d = idx >> 3;
            const int c = idx & 7;
            bf16x8 w;
            #pragma unroll
            for (int j = 0; j < 8; ++j) w[j] = s[c * 8 + j][d];
            *(bf16x8*)&vT[(size_t)(h * HD_ + d) * T_ + tb * 64 + c * 8] = w;
        }
    }
}

// ---------------------------------------------------------------- attention: prefill (x<40) + decode (x>=40)
__global__ __launch_bounds__(256)
void attn_kernel(const __bf16* __restrict__ q16, const __bf16* __restrict__ k16,
                 const __bf16* __restrict__ v16, const __bf16* __restrict__ vT,
                 const float* __restrict__ kc, const float* __restrict__ vc,
                 const int* __restrict__ kv_lens,
                 const float* __restrict__ cost, const float* __restrict__ sint,
                 __bf16* __restrict__ attn16)
{
    const int h = blockIdx.y;
    const int tid = threadIdx.x, lane = tid & 63, wid = tid >> 6;

    if (blockIdx.x < 40) {
        // ======================= prefill (MFMA flash, K/V dbuf) =======================
        const int qb = blockIdx.x;
        int soff, qoff;
        if      (qb < 16) { soff = 0;    qoff = qb * 64; }
        else if (qb < 24) { soff = 1024; qoff = (qb - 16) * 64; }
        else if (qb < 36) { soff = 1536; qoff = (qb - 24) * 64; }
        else              { soff = 2304; qoff = (qb - 36) * 64; }

        __shared__ __align__(16) __bf16 Kl[2][64 * 128];
        __shared__ __align__(16) __bf16 Vl[2][128 * 64];
        __shared__ __align__(16) __bf16 Pl[4][16 * 64];

        const int fr = lane & 15, fq = lane >> 4;
        const int grow0 = soff + qoff + wid * 16;
        bf16x8 qf[4];
        #pragma unroll
        for (int ks = 0; ks < 4; ++ks)
            qf[ks] = *(const bf16x8*)&q16[(size_t)(grow0 + fr) * H_ + h * HD_ + ks * 32 + fq * 8];

        auto stageK = [&](int buf, int t) {
            const int kt = t * 64;
            #pragma unroll
            for (int i = 0; i < 4; ++i) {
                const int chunk = i * 256 + tid;
                const int row = chunk >> 4, c = chunk & 15;
                async_cp16(k16 + (size_t)(soff + kt + row) * H_ + h * HD_ + ((c ^ (row & 7)) * 8),
                           Kl[buf] + (size_t)(i * 256 + wid * 64) * 8);
            }
        };
        auto stageV = [&](int buf, int t) {
            const int kt = t * 64;
            #pragma unroll
            for (int i = 0; i < 4; ++i) {
                const int chunk = i * 256 + tid;
                const int row = chunk >> 3, c = chunk & 7;
                async_cp16(vT + (size_t)(h * HD_ + row) * T_ + soff + kt + ((c ^ (row & 7)) * 8),
                           Vl[buf] + (size_t)(i * 256 + wid * 64) * 8);
            }
        };

        float m[4], l[4];
        #pragma unroll
        for (int r = 0; r < 4; ++r) { m[r] = -1e30f; l[r] = 0.f; }
        f32x4 o[8] = {};

        const int ntiles = qoff / 64 + 1;
        stageK(0, 0); stageV(0, 0);
        if (ntiles > 1) {
            stageK(1, 1); stageV(1, 1);
            asm volatile("s_waitcnt vmcnt(8)");
        } else {
            asm volatile("s_waitcnt vmcnt(0)");
        }
        __builtin_amdgcn_sched_barrier(0);
        __builtin_amdgcn_s_barrier();

        for (int t = 0; t < ntiles; ++t) {
            const int b = t & 1;
            const int kt = t * 64;

            f32x4 s[4] = {};
            __builtin_amdgcn_s_setprio(1);
            #pragma unroll
            for (int sub = 0; sub < 4; ++sub)
                #pragma unroll
                for (int ks = 0; ks < 4; ++ks) {
                    bf16x8 bk = *(const bf16x8*)&Kl[b][(sub * 16 + fr) * 128 + (((ks * 4 + fq) ^ (fr & 7)) * 8)];
                    s[sub] = __builtin_amdgcn_mfma_f32_16x16x32_bf16(qf[ks], bk, s[sub], 0, 0, 0);
                }
            __builtin_amdgcn_s_setprio(0);

            float p[4][4];
            #pragma unroll
            for (int sub = 0; sub < 4; ++sub)
                #pragma unroll
                for (int r = 0; r < 4; ++r) {
                    const int qpos = qoff + wid * 16 + fq * 4 + r;
                    const int kpos = kt + sub * 16 + fr;
                    p[sub][r] = (kpos <= qpos) ? s[sub][r] * SCALE_ : -1e30f;
                }
            float tm2[4];
            #pragma unroll
            for (int r = 0; r < 4; ++r) {
                float tm = fmaxf(fmaxf(p[0][r], p[1][r]), fmaxf(p[2][r], p[3][r]));
                tm = fmaxf(tm, __shfl_xor(tm, 1));
                tm = fmaxf(tm, __shfl_xor(tm, 2));
                tm = fmaxf(tm, __shfl_xor(tm, 4));
                tm = fmaxf(tm, __shfl_xor(tm, 8));
                tm2[r] = tm;
            }
            bool need = false;
            #pragma unroll
            for (int r = 0; r < 4; ++r) need |= (tm2[r] > m[r] + 8.f);
            if (__any(need)) {
                #pragma unroll
                for (int r = 0; r < 4; ++r) {
                    const float mn = fmaxf(m[r], tm2[r]);
                    const float f  = __expf(m[r] - mn);
                    m[r] = mn;
                    l[r] *= f;
                    #pragma unroll
                    for (int c = 0; c < 8; ++c) o[c][r] *= f;
                }
            }
            #pragma unroll
            for (int r = 0; r < 4; ++r) {
                float ls = 0.f;
                #pragma unroll
                for (int sub = 0; sub < 4; ++sub) {
                    p[sub][r] = __expf(p[sub][r] - m[r]);
                    ls += p[sub][r];
                }
                l[r] += ls;
            }

            #pragma unroll
            for (int sub = 0; sub < 4; ++sub)
                #pragma unroll
                for (int r = 0; r < 4; ++r) {
                    const int qr = fq * 4 + r;
                    Pl[wid][qr * 64 + ((sub * 16 + fr) ^ ((qr & 7) << 3))] = (__bf16)p[sub][r];
                }
            bf16x8 pa[2];
            #pragma unroll
            for (int a = 0; a < 2; ++a)
                pa[a] = *(const bf16x8*)&Pl[wid][fr * 64 + (((a * 4 + fq) ^ (fr & 7)) * 8)];

            __builtin_amdgcn_s_setprio(1);
            #pragma unroll
            for (int a = 0; a < 2; ++a)
                #pragma unroll
                for (int c = 0; c < 8; ++c) {
                    bf16x8 bv = *(const bf16x8*)&Vl[b][(c * 16 + fr) * 64 + (((a * 4 + fq) ^ (fr & 7)) * 8)];
                    o[c] = __builtin_amdgcn_mfma_f32_16x16x32_bf16(pa[a], bv, o[c], 0, 0, 0);
                }
            __builtin_amdgcn_s_setprio(0);

            __builtin_amdgcn_s_barrier();
            __builtin_amdgcn_sched_barrier(0);
            if (t + 2 < ntiles) { stageK(b, t + 2); stageV(b, t + 2); }
            if (t + 1 < ntiles) {
                if (t + 2 < ntiles) asm volatile("s_waitcnt vmcnt(8)");
                else                asm volatile("s_waitcnt vmcnt(0)");
                __builtin_amdgcn_sched_barrier(0);
                __builtin_amdgcn_s_barrier();
            }
        }

        float inv[4];
        #pragma unroll
        for (int r = 0; r < 4; ++r) {
            float ls = l[r];
            ls += __shfl_xor(ls, 1); ls += __shfl_xor(ls, 2);
            ls += __shfl_xor(ls, 4); ls += __shfl_xor(ls, 8);
            inv[r] = 1.f / ls;
        }
        #pragma unroll
        for (int c = 0; c < 8; ++c)
            #pragma unroll
            for (int r = 0; r < 4; ++r)
                attn16[(size_t)(grow0 + fq * 4 + r) * H_ + h * HD_ + c * 16 + fr] = (__bf16)(o[c][r] * inv[r]);
    } else {
        // ======================= decode =======================
        const int b = blockIdx.x - 40;
        const int kvlen = kv_lens[b];
        const int L = kvlen + 1;
        const int w = wid;

        __shared__ float sc_s[LMAX_];
        __shared__ float red[4];
        __shared__ float oacc[HD_];

        const __bf16* qrow = q16 + (size_t)(DOFF_ + b) * H_ + h * HD_;
        const float q1 = (float)qrow[lane], q2 = (float)qrow[lane + 64];
        const __bf16* kdrow = k16 + (size_t)(DOFF_ + b) * H_ + h * HD_;

        for (int l = w; l < L; l += 4) {
            float k1, k2;
            if (l == kvlen) { k1 = (float)kdrow[lane]; k2 = (float)kdrow[lane + 64]; }
            else {
                const float* src = kc + (((size_t)b * LMAX_ + l) * NH_ + h) * HD_;
                k1 = src[lane]; k2 = src[lane + 64];
            }
            const float c = cost[l * 64 + lane], s = sint[l * 64 + lane];
            float d = q1 * (k1 * c - k2 * s) + q2 * (k2 * c + k1 * s);
            #pragma unroll
            for (int off = 1; off < 64; off <<= 1) d += __shfl_xor(d, off);
            if (lane == 0) sc_s[l] = d * SCALE_;
        }
        __syncthreads();

        float mx = -1e30f;
        for (int i = tid; i < L; i += 256) mx = fmaxf(mx, sc_s[i]);
        #pragma unroll
        for (int off = 1; off < 64; off <<= 1) mx = fmaxf(mx, __shfl_xor(mx, off));
        if (lane == 0) red[w] = mx;
        __syncthreads();
        mx = fmaxf(fmaxf(red[0], red[1]), fmaxf(red[2], red[3]));
        __syncthreads();

        float sum = 0.f;
        for (int i = tid; i < L; i += 256) { const float e = __expf(sc_s[i] - mx); sc_s[i] = e; sum += e; }
        #pragma unroll
        for (int off = 1; off < 64; off <<= 1) sum += __shfl_xor(sum, off);
        if (lane == 0) red[w] = sum;
        __syncthreads();
        sum = red[0] + red[1] + red[2] + red[3];
        const float inv = 1.f / sum;

        const int d = tid & 127, team = tid >> 7;
        const __bf16* vdrow = v16 + (size_t)(DOFF_ + b) * H_ + h * HD_;
        float acc = 0.f;
        for (int l = team; l < L; l += 2) {
            float vv;
            if (l == kvlen) vv = (float)vdrow[d];
            else            vv = vc[(((size_t)b * LMAX_ + l) * NH_ + h) * HD_ + d];
            acc += sc_s[l] * vv;
        }
        if (team == 1) oacc[d] = acc;
        __syncthreads();
        if (team == 0) attn16[(size_t)(DOFF_ + b) * H_ + h * HD_ + d] = (__bf16)((acc + oacc[d]) * inv);
    }
}

// ---------------------------------------------------------------- host launch
extern "C" void kernel_launch(void* const* d_in, const int* in_sizes, int n_in,
                              void* d_out, int out_size, void* d_ws, size_t ws_size,
                              hipStream_t stream)
{
    const float* hs     = (const float*)d_in[0];
    const float* wq     = (const float*)d_in[1];
    const float* wk     = (const float*)d_in[2];
    const float* wv     = (const float*)d_in[3];
    const float* wo     = (const float*)d_in[4];
    const float* la_q   = (const float*)d_in[5];
    const float* lb_q   = (const float*)d_in[6];
    const float* la_k   = (const float*)d_in[7];
    const float* lb_k   = (const float*)d_in[8];
    const float* la_v   = (const float*)d_in[9];
    const float* lb_v   = (const float*)d_in[10];
    const float* la_o   = (const float*)d_in[11];
    const float* lb_o   = (const float*)d_in[12];
    const float* kcache = (const float*)d_in[13];
    const float* vcache = (const float*)d_in[14];
    const int*   kvlen  = (const int*)d_in[15];
    float* out = (float*)d_out;

    float*  costab = (float*)d_ws;
    float*  sintab = costab + 1024 * 64;
    __bf16* TMP16  = (__bf16*)(sintab + 1024 * 64);       // [3][MPAD][64]
    __bf16* TMPo16 = TMP16 + (size_t)3 * MPAD_ * 64;      // [MPAD][64]
    __bf16* WB16   = TMPo16 + (size_t)MPAD_ * 64;         // [12288][64]
    __bf16* WBo16  = WB16 + (size_t)3 * H_ * 64;          // [4352][64]
    __bf16* q16    = WBo16 + (size_t)4352 * 64;           // [T][H]
    __bf16* k16    = q16 + (size_t)T_ * H_;
    __bf16* v16    = k16 + (size_t)T_ * H_;
    __bf16* hsb    = v16 + (size_t)T_ * H_;               // [MPAD][H]: hs bf16, later attn16
    __bf16* wT     = hsb + (size_t)MPAD_ * H_;            // [3][H][H]
    __bf16* woT    = wT + (size_t)3 * H_ * H_;            // [H][H]
    __bf16* vT     = woT + (size_t)H_ * H_;               // [H][T]
    __bf16* attn16 = hsb;

    prep1_kernel<<<dim3(T_ + 16384 + 64 + 256), dim3(256), 0, stream>>>(
        hs, hsb, la_q, la_k, la_v, TMP16,
        wq, wk, wv, wo, wT, woT,
        lb_q, lb_k, lb_v, lb_o, WB16, WBo16, costab, sintab);
    gemm_qkv<<<dim3(21, 48), dim3(512), 0, stream>>>(
        hsb, wT, TMP16, WB16, q16, k16, v16, T_);
    post1_kernel<<<dim3(T_ + 1280), dim3(256), 0, stream>>>(
        q16, k16, v16, vT, kvlen, costab, sintab);
    attn_kernel<<<dim3(72, 32), dim3(256), 0, stream>>>(
        q16, k16, v16, vT, kcache, vcache, kvlen, costab, sintab, attn16);
    lora_tmp_bf16_kernel<<<dim3(T_), dim3(256), 0, stream>>>(attn16, la_o, TMPo16);
    gemm_out<<<dim3(11, 22), dim3(512), 0, stream>>>(
        attn16, woT, TMPo16, WBo16, out, T_, H_);
}

// Round 11
// 1076.980 us; speedup vs baseline: 1.0105x; 1.0105x over previous
//
#include <hip/hip_runtime.h>
#include <hip/hip_bf16.h>

// LlamaAttentionWithLora on MI355X — round 11.
// Prefill attention rebuilt as BARRIER-FREE per-wave flash (wave = 16 q-rows x head,
// KVBLK=32, K/V^T read line-coalesced directly from global/L2, LDS only for a 1KB/wave
// P buffer). attn merge reverted (decode separate again). prep1/post1/GEMMs as R10/R9.

#define H_    4096
#define NH_   32
#define HD_   128
#define T_    2592
#define DOFF_ 2560
#define DEC_  32
#define LMAX_ 512
#define RANK_ 16
#define MPAD_ 2816

__constant__ float SCALE_ = 0.08838834764831845f; // 128^-0.5

typedef __bf16 bf16x8 __attribute__((ext_vector_type(8)));
typedef __bf16 bf16x4 __attribute__((ext_vector_type(4)));
typedef float  f32x4  __attribute__((ext_vector_type(4)));

__device__ __forceinline__ void async_cp16(const __bf16* g, __bf16* l) {
    __builtin_amdgcn_global_load_lds(
        (const __attribute__((address_space(1))) void*)g,
        (__attribute__((address_space(3))) void*)l, 16, 0, 0);
}

// ---------------------------------------------------------------- prep1: fused pre-GEMM work
__global__ __launch_bounds__(256)
void prep1_kernel(const float* __restrict__ X, __bf16* __restrict__ Xb,
                  const float* __restrict__ la0, const float* __restrict__ la1,
                  const float* __restrict__ la2, __bf16* __restrict__ TMP16,
                  const float* __restrict__ wq, const float* __restrict__ wk,
                  const float* __restrict__ wv, const float* __restrict__ wo,
                  __bf16* __restrict__ wT, __bf16* __restrict__ woT,
                  const float* __restrict__ lbq, const float* __restrict__ lbk,
                  const float* __restrict__ lbv, const float* __restrict__ lbo,
                  __bf16* __restrict__ WB16, __bf16* __restrict__ WBo16,
                  float* __restrict__ cost, float* __restrict__ sint)
{
    const int bid = blockIdx.x;
    const int tid = threadIdx.x;

    if (bid < T_) {
        const int r = bid;
        const float* xr = X + (size_t)r * H_;
        __bf16* br = Xb + (size_t)r * H_;
        #pragma unroll
        for (int i = 0; i < 4; ++i) {
            float4 v = ((const float4*)xr)[tid + i * 256];
            bf16x4 w; w[0] = (__bf16)v.x; w[1] = (__bf16)v.y; w[2] = (__bf16)v.z; w[3] = (__bf16)v.w;
            ((bf16x4*)br)[tid + i * 256] = w;
        }
        const int si = (r < 648) ? 0 : (r < 1296 ? 1 : (r < 1944 ? 2 : 3));
        const int c    = tid & 15;
        const int part = tid >> 4;
        const float* wa0 = la0 + (size_t)si * H_ * RANK_;
        const float* wa1 = la1 + (size_t)si * H_ * RANK_;
        const float* wa2 = la2 + (size_t)si * H_ * RANK_;
        float s0 = 0.f, s1 = 0.f, s2 = 0.f;
        const int h0 = part * 256;
        for (int h = h0; h < h0 + 256; ++h) {
            const float xv = xr[h];
            s0 += xv * wa0[(size_t)h * RANK_ + c];
            s1 += xv * wa1[(size_t)h * RANK_ + c];
            s2 += xv * wa2[(size_t)h * RANK_ + c];
        }
        __shared__ float red[3][16][17];
        red[0][part][c] = s0; red[1][part][c] = s1; red[2][part][c] = s2;
        __syncthreads();
        if (tid < 192) {
            const int z = tid >> 6, cc = tid & 63;
            float t = 0.f;
            if ((cc >> 4) == si) {
                #pragma unroll
                for (int p = 0; p < 16; ++p) t += red[z][p][cc & 15];
            }
            TMP16[((size_t)z * MPAD_ + r) * 64 + cc] = (__bf16)t;
        }
    } else if (bid < T_ + 16384) {
        const int t = bid - T_;
        const int z = t >> 12;
        const int rem = t & 4095;
        const int bx = (rem >> 6) * 64;
        const int by = (rem & 63) * 64;
        const float* W = (z == 0) ? wq : (z == 1 ? wk : (z == 2 ? wv : wo));
        __bf16* To = (z < 3) ? wT + (size_t)z * H_ * H_ : woT;
        __shared__ float s[64][65];
        #pragma unroll
        for (int i = 0; i < 4; ++i) {
            const int idx = i * 256 + tid;
            const int r  = idx >> 4;
            const int c4 = (idx & 15) * 4;
            float4 v = *(const float4*)&W[(size_t)(by + r) * H_ + bx + c4];
            s[r][c4] = v.x; s[r][c4 + 1] = v.y; s[r][c4 + 2] = v.z; s[r][c4 + 3] = v.w;
        }
        __syncthreads();
        #pragma unroll
        for (int i = 0; i < 2; ++i) {
            const int idx = i * 256 + tid;
            const int n  = idx >> 3;
            const int kc = (idx & 7) * 8;
            bf16x8 w;
            #pragma unroll
            for (int j = 0; j < 8; ++j) w[j] = (__bf16)s[kc + j][n];
            *(bf16x8*)&To[(size_t)(bx + n) * H_ + by + kc] = w;
        }
    } else if (bid < T_ + 16384 + 64) {
        const int t = bid - (T_ + 16384);
        const int z = t >> 4;
        const int n = (t & 15) * 256 + tid;
        const float* lb = (z == 0) ? lbq : (z == 1 ? lbk : (z == 2 ? lbv : lbo));
        __bf16* dst = (z < 3) ? WB16 + ((size_t)z * H_ + n) * 64 : WBo16 + (size_t)n * 64;
        __bf16 row[64];
        #pragma unroll
        for (int si = 0; si < 4; ++si)
            #pragma unroll
            for (int c = 0; c < 16; ++c)
                row[si * 16 + c] = (__bf16)lb[((size_t)si * 16 + c) * H_ + n];
        #pragma unroll
        for (int i = 0; i < 8; ++i) *(bf16x8*)&dst[i * 8] = *(const bf16x8*)&row[i * 8];
    } else {
        const int t = bid - (T_ + 16384 + 64);
        const int p = t * 4 + (tid >> 6);
        const int i = tid & 63;
        const float inv = powf(10000.f, -(float)(2 * i) / (float)HD_);
        const float a = (float)p * inv;
        cost[p * 64 + i] = cosf(a);
        sint[p * 64 + i] = sinf(a);
    }
}

// ---------------------------------------------------------------- QKV GEMM (128x256, BK=64, 3-buf ring) + fused lora, bf16 out
__global__ __launch_bounds__(512, 2)
void gemm_qkv(const __bf16* __restrict__ A, const __bf16* __restrict__ Bt,
              const __bf16* __restrict__ TMP16, const __bf16* __restrict__ WB16,
              __bf16* __restrict__ O0, __bf16* __restrict__ O1, __bf16* __restrict__ O2, int M)
{
    const int hw = blockIdx.y * 21 + blockIdx.x;
    const int work = (hw & 7) * 126 + (hw >> 3);
    const int bm0 = (work % 21) * 128;
    const int bn0 = (work / 21) * 256;

    __shared__ __align__(16) __bf16 Asl[3][128 * 64];
    __shared__ __align__(16) __bf16 Bsl[3][256 * 64];

    const int tid = threadIdx.x, lane = tid & 63, wid = tid >> 6;
    const int wr = wid >> 2, wc = wid & 3;
    const int fr = lane & 15, fq = lane >> 4;

    int arow[2], aoff[2], brow[4], boff[4];
    #pragma unroll
    for (int i = 0; i < 2; ++i) {
        const int ci = i * 512 + tid;
        arow[i] = ci >> 3;
        aoff[i] = ((ci & 7) ^ (arow[i] & 7)) * 8;
    }
    #pragma unroll
    for (int i = 0; i < 4; ++i) {
        const int ci = i * 512 + tid;
        brow[i] = ci >> 3;
        boff[i] = ((ci & 7) ^ (brow[i] & 7)) * 8;
    }
    const __bf16* Ab = A  + (size_t)bm0 * H_;
    const __bf16* Bb = Bt + (size_t)bn0 * H_;

    auto stageA = [&](int buf, int kt2) {
        const int kb = kt2 * 64;
        #pragma unroll
        for (int i = 0; i < 2; ++i)
            async_cp16(Ab + (size_t)arow[i] * H_ + kb + aoff[i],
                       &Asl[buf][(i * 512 + wid * 64) * 8]);
    };
    auto stageB1 = [&](int buf, int kt2) {
        async_cp16(Bb + (size_t)brow[0] * H_ + kt2 * 64 + boff[0],
                   &Bsl[buf][(wid * 64) * 8]);
    };
    auto stageB3 = [&](int buf, int kt2) {
        const int kb = kt2 * 64;
        #pragma unroll
        for (int i = 1; i < 4; ++i)
            async_cp16(Bb + (size_t)brow[i] * H_ + kb + boff[i],
                       &Bsl[buf][(i * 512 + wid * 64) * 8]);
    };
    auto rdA = [&](int buf, int kh, int mi) -> bf16x8 {
        const int row = wr * 64 + mi * 16 + fr;
        const int pc  = (kh * 4 + fq) ^ (row & 7);
        return *(const bf16x8*)&Asl[buf][row * 64 + pc * 8];
    };
    auto rdB = [&](int buf, int kh, int nj) -> bf16x8 {
        const int row = wc * 64 + nj * 16 + fr;
        const int pc  = (kh * 4 + fq) ^ (row & 7);
        return *(const bf16x8*)&Bsl[buf][row * 64 + pc * 8];
    };

    f32x4 acc[4][4] = {};

    stageA(0, 0); stageB1(0, 0); stageB3(0, 0);
    stageA(1, 1); stageB1(1, 1); stageB3(1, 1);
    asm volatile("s_waitcnt vmcnt(6)");
    __builtin_amdgcn_sched_barrier(0);
    __builtin_amdgcn_s_barrier();

    const int NT = H_ / 64;
    int cur = 0, nxt = 2;
    for (int kt = 0; kt < NT; ++kt) {
        const bool pf = (kt + 2 < NT);
        bf16x8 af[4], bfr[4];

        #pragma unroll
        for (int mi = 0; mi < 4; ++mi) af[mi] = rdA(cur, 0, mi);
        #pragma unroll
        for (int nj = 0; nj < 4; ++nj) bfr[nj] = rdB(cur, 0, nj);
        if (pf) { stageA(nxt, kt + 2); stageB1(nxt, kt + 2); }
        __builtin_amdgcn_s_barrier();
        asm volatile("s_waitcnt lgkmcnt(0)");
        __builtin_amdgcn_sched_barrier(0);
        __builtin_amdgcn_s_setprio(1);
        #pragma unroll
        for (int mi = 0; mi < 4; ++mi)
            #pragma unroll
            for (int nj = 0; nj < 4; ++nj)
                acc[mi][nj] = __builtin_amdgcn_mfma_f32_16x16x32_bf16(af[mi], bfr[nj], acc[mi][nj], 0, 0, 0);
        __builtin_amdgcn_s_setprio(0);
        __builtin_amdgcn_s_barrier();

        #pragma unroll
        for (int mi = 0; mi < 4; ++mi) af[mi] = rdA(cur, 1, mi);
        #pragma unroll
        for (int nj = 0; nj < 4; ++nj) bfr[nj] = rdB(cur, 1, nj);
        if (pf) stageB3(nxt, kt + 2);
        __builtin_amdgcn_s_barrier();
        asm volatile("s_waitcnt lgkmcnt(0)");
        __builtin_amdgcn_sched_barrier(0);
        __builtin_amdgcn_s_setprio(1);
        #pragma unroll
        for (int mi = 0; mi < 4; ++mi)
            #pragma unroll
            for (int nj = 0; nj < 4; ++nj)
                acc[mi][nj] = __builtin_amdgcn_mfma_f32_16x16x32_bf16(af[mi], bfr[nj], acc[mi][nj], 0, 0, 0);
        __builtin_amdgcn_s_setprio(0);
        if (pf)               asm volatile("s_waitcnt vmcnt(6)");
        else if (kt + 1 < NT) asm volatile("s_waitcnt vmcnt(0)");
        __builtin_amdgcn_sched_barrier(0);
        __builtin_amdgcn_s_barrier();

        cur = (cur == 2) ? 0 : cur + 1;
        nxt = (nxt == 2) ? 0 : nxt + 1;
    }

    const int colbase = bn0 + wc * 64;
    const int mat = colbase >> 12;
    __bf16* O = (mat == 0) ? O0 : (mat == 1 ? O1 : O2);
    const __bf16* TPm = TMP16 + (size_t)mat * MPAD_ * 64;
    bf16x8 aT[4][2], bW[4][2];
    #pragma unroll
    for (int mi = 0; mi < 4; ++mi)
        #pragma unroll
        for (int kh = 0; kh < 2; ++kh)
            aT[mi][kh] = *(const bf16x8*)&TPm[(size_t)(bm0 + wr * 64 + mi * 16 + fr) * 64 + kh * 32 + fq * 8];
    #pragma unroll
    for (int nj = 0; nj < 4; ++nj)
        #pragma unroll
        for (int kh = 0; kh < 2; ++kh)
            bW[nj][kh] = *(const bf16x8*)&WB16[(size_t)(colbase + nj * 16 + fr) * 64 + kh * 32 + fq * 8];
    #pragma unroll
    for (int mi = 0; mi < 4; ++mi)
        #pragma unroll
        for (int nj = 0; nj < 4; ++nj) {
            acc[mi][nj] = __builtin_amdgcn_mfma_f32_16x16x32_bf16(aT[mi][0], bW[nj][0], acc[mi][nj], 0, 0, 0);
            acc[mi][nj] = __builtin_amdgcn_mfma_f32_16x16x32_bf16(aT[mi][1], bW[nj][1], acc[mi][nj], 0, 0, 0);
        }
    #pragma unroll
    for (int mi = 0; mi < 4; ++mi)
        #pragma unroll
        for (int nj = 0; nj < 4; ++nj) {
            const int cc = (colbase + nj * 16 + fr) & 4095;
            #pragma unroll
            for (int rr = 0; rr < 4; ++rr) {
                const int row = bm0 + wr * 64 + mi * 16 + fq * 4 + rr;
                if (row < M) O[(size_t)row * H_ + cc] = (__bf16)acc[mi][nj][rr];
            }
        }
}

// ---------------------------------------------------------------- O-proj GEMM (256x192, BK=64) + fused lora, f32 out
__global__ __launch_bounds__(512, 2)
void gemm_out(const __bf16* __restrict__ A, const __bf16* __restrict__ Bt,
              const __bf16* __restrict__ TMPo16, const __bf16* __restrict__ WBo16,
              float* __restrict__ C, int M, int Ntot)
{
    const int NY = gridDim.y;
    const int total = gridDim.x * NY;
    const int bid = blockIdx.x * NY + blockIdx.y;
    const int q = total >> 3, r8 = total & 7;
    const int xcd = bid & 7, j = bid >> 3;
    const int swz = (xcd < r8 ? xcd * (q + 1) : r8 * (q + 1) + (xcd - r8) * q) + j;
    const int bm0 = (swz / NY) * 256;
    const int bn0 = (swz % NY) * 192;

    __shared__ __align__(16) __bf16 Asl[2][256 * 64];
    __shared__ __align__(16) __bf16 Bsl[2][192 * 64];

    const int tid = threadIdx.x, lane = tid & 63, wid = tid >> 6;
    const int wr = wid >> 2, wc = wid & 3;
    const int fr = lane & 15, fq = lane >> 4;

    int arow[4], aoff[4], brow[3], boff[3];
    #pragma unroll
    for (int i = 0; i < 4; ++i) {
        const int ci = i * 512 + tid;
        arow[i] = ci >> 3;
        aoff[i] = ((ci & 7) ^ (arow[i] & 7)) * 8;
    }
    #pragma unroll
    for (int i = 0; i < 3; ++i) {
        const int ci = i * 512 + tid;
        brow[i] = ci >> 3;
        boff[i] = ((ci & 7) ^ (brow[i] & 7)) * 8;
    }
    const __bf16* Ab = A  + (size_t)bm0 * H_;
    const __bf16* Bb = Bt + (size_t)bn0 * H_;

    auto stage = [&](int buf, int kt1) {
        const int kb = kt1 * 64;
        #pragma unroll
        for (int i = 0; i < 4; ++i)
            async_cp16(Ab + (size_t)arow[i] * H_ + kb + aoff[i],
                       &Asl[buf][(i * 512 + wid * 64) * 8]);
        #pragma unroll
        for (int i = 0; i < 3; ++i)
            async_cp16(Bb + (size_t)brow[i] * H_ + kb + boff[i],
                       &Bsl[buf][(i * 512 + wid * 64) * 8]);
    };
    auto rdA = [&](int buf, int kh, int mi) -> bf16x8 {
        const int row = wr * 128 + mi * 16 + fr;
        const int kc  = kh * 4 + fq;
        return *(const bf16x8*)&Asl[buf][row * 64 + ((kc ^ (row & 7)) << 3)];
    };
    auto rdB = [&](int buf, int kh, int nj) -> bf16x8 {
        const int row = wc * 48 + nj * 16 + fr;
        const int kc  = kh * 4 + fq;
        return *(const bf16x8*)&Bsl[buf][row * 64 + ((kc ^ (row & 7)) << 3)];
    };

    f32x4 acc[8][3] = {};

    stage(0, 0);
    asm volatile("s_waitcnt vmcnt(0)");
    __builtin_amdgcn_sched_barrier(0);
    __builtin_amdgcn_s_barrier();

    const int NT = H_ / 64;
    for (int kt = 0; kt < NT; ++kt) {
        const int cur = kt & 1, nb = cur ^ 1;
        const bool pf = (kt + 1 < NT);
        bf16x8 af[8], bfr[3];

        #pragma unroll
        for (int mi = 0; mi < 8; ++mi) af[mi] = rdA(cur, 0, mi);
        #pragma unroll
        for (int nj = 0; nj < 3; ++nj) bfr[nj] = rdB(cur, 0, nj);
        if (pf) stage(nb, kt + 1);
        __builtin_amdgcn_s_barrier();
        asm volatile("s_waitcnt lgkmcnt(0)");
        __builtin_amdgcn_sched_barrier(0);
        __builtin_amdgcn_s_setprio(1);
        #pragma unroll
        for (int mi = 0; mi < 8; ++mi)
            #pragma unroll
            for (int nj = 0; nj < 3; ++nj)
                acc[mi][nj] = __builtin_amdgcn_mfma_f32_16x16x32_bf16(af[mi], bfr[nj], acc[mi][nj], 0, 0, 0);
        __builtin_amdgcn_s_setprio(0);
        __builtin_amdgcn_s_barrier();

        #pragma unroll
        for (int mi = 0; mi < 8; ++mi) af[mi] = rdA(cur, 1, mi);
        #pragma unroll
        for (int nj = 0; nj < 3; ++nj) bfr[nj] = rdB(cur, 1, nj);
        __builtin_amdgcn_s_barrier();
        asm volatile("s_waitcnt lgkmcnt(0)");
        __builtin_amdgcn_sched_barrier(0);
        __builtin_amdgcn_s_setprio(1);
        #pragma unroll
        for (int mi = 0; mi < 8; ++mi)
            #pragma unroll
            for (int nj = 0; nj < 3; ++nj)
                acc[mi][nj] = __builtin_amdgcn_mfma_f32_16x16x32_bf16(af[mi], bfr[nj], acc[mi][nj], 0, 0, 0);
        __builtin_amdgcn_s_setprio(0);
        asm volatile("s_waitcnt vmcnt(0)");
        __builtin_amdgcn_sched_barrier(0);
        __builtin_amdgcn_s_barrier();
    }

    const int colw = bn0 + wc * 48;
    bf16x8 aT[8][2], bW[3][2];
    #pragma unroll
    for (int mi = 0; mi < 8; ++mi)
        #pragma unroll
        for (int kh = 0; kh < 2; ++kh)
            aT[mi][kh] = *(const bf16x8*)&TMPo16[(size_t)(bm0 + wr * 128 + mi * 16 + fr) * 64 + kh * 32 + fq * 8];
    #pragma unroll
    for (int nj = 0; nj < 3; ++nj)
        #pragma unroll
        for (int kh = 0; kh < 2; ++kh)
            bW[nj][kh] = *(const bf16x8*)&WBo16[(size_t)(colw + nj * 16 + fr) * 64 + kh * 32 + fq * 8];
    #pragma unroll
    for (int mi = 0; mi < 8; ++mi)
        #pragma unroll
        for (int nj = 0; nj < 3; ++nj) {
            acc[mi][nj] = __builtin_amdgcn_mfma_f32_16x16x32_bf16(aT[mi][0], bW[nj][0], acc[mi][nj], 0, 0, 0);
            acc[mi][nj] = __builtin_amdgcn_mfma_f32_16x16x32_bf16(aT[mi][1], bW[nj][1], acc[mi][nj], 0, 0, 0);
        }
    #pragma unroll
    for (int mi = 0; mi < 8; ++mi)
        #pragma unroll
        for (int nj = 0; nj < 3; ++nj) {
            const int col = colw + nj * 16 + fr;
            if (col < Ntot) {
                #pragma unroll
                for (int rr = 0; rr < 4; ++rr) {
                    const int row = bm0 + wr * 128 + mi * 16 + fq * 4 + rr;
                    if (row < M) C[(size_t)row * H_ + col] = acc[mi][nj][rr];
                }
            }
        }
}

// ---------------------------------------------------------------- LoRA stage 1 (bf16 X) -> TMPo16[r][64]
__global__ __launch_bounds__(256)
void lora_tmp_bf16_kernel(const __bf16* __restrict__ X,
                          const float* __restrict__ la, __bf16* __restrict__ TMPo16)
{
    const int r = blockIdx.x;
    const int si = (r < 648) ? 0 : (r < 1296 ? 1 : (r < 1944 ? 2 : 3));
    const float* wa = la + (size_t)si * H_ * RANK_;
    const int c    = threadIdx.x & 15;
    const int part = threadIdx.x >> 4;
    const __bf16* xr = X + (size_t)r * H_;
    float s = 0.f;
    const int h0 = part * 256;
    for (int h = h0; h < h0 + 256; ++h) s += (float)xr[h] * wa[(size_t)h * RANK_ + c];
    __shared__ float red[16][17];
    red[part][c] = s;
    __syncthreads();
    if (threadIdx.x < 64) {
        const int cc = threadIdx.x;
        float t = 0.f;
        if ((cc >> 4) == si) {
            #pragma unroll
            for (int p = 0; p < 16; ++p) t += red[p][cc & 15];
        }
        TMPo16[(size_t)r * 64 + cc] = (__bf16)t;
    }
}

// ---------------------------------------------------------------- post1: rope16 + transpose_v fused
__global__ __launch_bounds__(256)
void post1_kernel(__bf16* __restrict__ q16, __bf16* __restrict__ k16,
                  const __bf16* __restrict__ v16, __bf16* __restrict__ vT,
                  const int* __restrict__ kv_lens,
                  const float* __restrict__ cost, const float* __restrict__ sint)
{
    const int bid = blockIdx.x;
    const int tid = threadIdx.x;

    if (bid < T_) {
        const int r = bid;
        int pos; bool dok;
        if (r < DOFF_) {
            if      (r < 1024) pos = r;
            else if (r < 1536) pos = r - 1024;
            else if (r < 2304) pos = r - 1536;
            else               pos = r - 2304;
            dok = true;
        } else {
            pos = kv_lens[r - DOFF_];
            dok = false;
        }
        const int h = tid >> 3, sub = tid & 7;
        const int i0 = sub * 8;
        const size_t b1 = (size_t)r * H_ + h * HD_ + i0;
        const size_t b2 = b1 + 64;

        float cs[8], sn[8];
        #pragma unroll
        for (int j = 0; j < 8; ++j) { cs[j] = cost[pos * 64 + i0 + j]; sn[j] = sint[pos * 64 + i0 + j]; }

        {
            bf16x8 x1 = *(const bf16x8*)&q16[b1], x2 = *(const bf16x8*)&q16[b2];
            bf16x8 o1, o2;
            #pragma unroll
            for (int j = 0; j < 8; ++j) {
                const float f1 = (float)x1[j], f2 = (float)x2[j];
                o1[j] = (__bf16)(f1 * cs[j] - f2 * sn[j]);
                o2[j] = (__bf16)(f2 * cs[j] + f1 * sn[j]);
            }
            *(bf16x8*)&q16[b1] = o1; *(bf16x8*)&q16[b2] = o2;
        }
        if (dok) {
            bf16x8 x1 = *(const bf16x8*)&k16[b1], x2 = *(const bf16x8*)&k16[b2];
            bf16x8 o1, o2;
            #pragma unroll
            for (int j = 0; j < 8; ++j) {
                const float f1 = (float)x1[j], f2 = (float)x2[j];
                o1[j] = (__bf16)(f1 * cs[j] - f2 * sn[j]);
                o2[j] = (__bf16)(f2 * cs[j] + f1 * sn[j]);
            }
            *(bf16x8*)&k16[b1] = o1; *(bf16x8*)&k16[b2] = o2;
        }
    } else {
        const int t = bid - T_;
        const int tb = t % 40;
        const int h  = t / 40;
        __shared__ __bf16 s[64][136];
        #pragma unroll
        for (int i = 0; i < 4; ++i) {
            const int idx = i * 256 + tid;
            const int row = idx >> 4;
            const int c8  = (idx & 15) * 8;
            *(bf16x8*)&s[row][c8] = *(const bf16x8*)&v16[(size_t)(tb * 64 + row) * H_ + h * HD_ + c8];
        }
        __syncthreads();
        #pragma unroll
        for (int i = 0; i < 4; ++i) {
            const int idx = i * 256 + tid;
            const int d = idx >> 3;
            const int c = idx & 7;
            bf16x8 w;
            #pragma unroll
            for (int j = 0; j < 8; ++j) w[j] = s[c * 8 + j][d];
            *(bf16x8*)&vT[(size_t)(h * HD_ + d) * T_ + tb * 64 + c * 8] = w;
        }
    }
}

// ---------------------------------------------------------------- prefill attention: barrier-free per-wave flash
// wave = (16 q-rows, head). KVBLK=32. K/V^T fragments loaded directly from global (L2).
// LDS only: per-wave 16x32 P buffer. No __syncthreads / s_barrier anywhere.
__global__ __launch_bounds__(256)
void prefill_attn_wave(const __bf16* __restrict__ q16, const __bf16* __restrict__ k16,
                       const __bf16* __restrict__ vT, __bf16* __restrict__ attn16)
{
    const int tid = threadIdx.x, lane = tid & 63, wid = tid >> 6;
    const int h = blockIdx.x / 40;
    const int g = (blockIdx.x % 40) * 4 + wid;     // 0..159 q-block16 index
    int soff, gq;
    if      (g < 64)  { soff = 0;    gq = g; }
    else if (g < 96)  { soff = 1024; gq = g - 64; }
    else if (g < 144) { soff = 1536; gq = g - 96; }
    else              { soff = 2304; gq = g - 144; }
    const int qoff = gq * 16;
    const int fr = lane & 15, fq = lane >> 4;

    __shared__ __align__(16) __bf16 Pl[4][16 * 32];
    __bf16* Plw = Pl[wid];

    const int grow0 = soff + qoff;
    bf16x8 qf[4];
    #pragma unroll
    for (int ks = 0; ks < 4; ++ks)
        qf[ks] = *(const bf16x8*)&q16[(size_t)(grow0 + fr) * H_ + h * HD_ + ks * 32 + fq * 8];

    float m[4], l[4];
    #pragma unroll
    for (int r = 0; r < 4; ++r) { m[r] = -1e30f; l[r] = 0.f; }
    f32x4 o[8] = {};

    const int ntiles = (qoff + 15) / 32 + 1;
    const __bf16* Kb = k16 + h * HD_;
    const __bf16* Vb = vT + (size_t)h * HD_ * T_;

    for (int t = 0; t < ntiles; ++t) {
        const int kt = t * 32;

        // QK^T: S[16q][32key], direct-global B fragments (line-coalesced: 16 rows x 64B)
        f32x4 s[2] = {};
        #pragma unroll
        for (int sub = 0; sub < 2; ++sub)
            #pragma unroll
            for (int ks = 0; ks < 4; ++ks) {
                bf16x8 bk = *(const bf16x8*)&Kb[(size_t)(soff + kt + sub * 16 + fr) * H_ + ks * 32 + fq * 8];
                s[sub] = __builtin_amdgcn_mfma_f32_16x16x32_bf16(qf[ks], bk, s[sub], 0, 0, 0);
            }

        float p[2][4];
        #pragma unroll
        for (int sub = 0; sub < 2; ++sub)
            #pragma unroll
            for (int r = 0; r < 4; ++r) {
                const int qpos = qoff + fq * 4 + r;
                const int kpos = kt + sub * 16 + fr;
                p[sub][r] = (kpos <= qpos) ? s[sub][r] * SCALE_ : -1e30f;
            }
        float tm2[4];
        #pragma unroll
        for (int r = 0; r < 4; ++r) {
            float tm = fmaxf(p[0][r], p[1][r]);
            tm = fmaxf(tm, __shfl_xor(tm, 1));
            tm = fmaxf(tm, __shfl_xor(tm, 2));
            tm = fmaxf(tm, __shfl_xor(tm, 4));
            tm = fmaxf(tm, __shfl_xor(tm, 8));
            tm2[r] = tm;
        }
        // defer-max (T13)
        bool need = false;
        #pragma unroll
        for (int r = 0; r < 4; ++r) need |= (tm2[r] > m[r] + 8.f);
        if (__any(need)) {
            #pragma unroll
            for (int r = 0; r < 4; ++r) {
                const float mn = fmaxf(m[r], tm2[r]);
                const float f  = __expf(m[r] - mn);
                m[r] = mn;
                l[r] *= f;
                #pragma unroll
                for (int c = 0; c < 8; ++c) o[c][r] *= f;
            }
        }
        #pragma unroll
        for (int r = 0; r < 4; ++r) {
            float ls = 0.f;
            #pragma unroll
            for (int sub = 0; sub < 2; ++sub) {
                p[sub][r] = __expf(p[sub][r] - m[r]);
                ls += p[sub][r];
            }
            l[r] += ls;
        }

        // P -> per-wave LDS (16B-chunk swizzled), reread as A fragment
        #pragma unroll
        for (int sub = 0; sub < 2; ++sub)
            #pragma unroll
            for (int r = 0; r < 4; ++r) {
                const int qr = fq * 4 + r;
                const int col = sub * 16 + fr;
                Plw[qr * 32 + ((((col >> 3) ^ (qr & 3)) & 3) * 8) + (col & 7)] = (__bf16)p[sub][r];
            }
        bf16x8 pa = *(const bf16x8*)&Plw[fr * 32 + (((fq ^ (fr & 3)) & 3) * 8)];

        // PV: O[16q][128d] += P @ V  (V^T direct-global B fragments, line-coalesced)
        #pragma unroll
        for (int c = 0; c < 8; ++c) {
            bf16x8 bv = *(const bf16x8*)&Vb[(size_t)(c * 16 + fr) * T_ + soff + kt + fq * 8];
            o[c] = __builtin_amdgcn_mfma_f32_16x16x32_bf16(pa, bv, o[c], 0, 0, 0);
        }
    }

    float inv[4];
    #pragma unroll
    for (int r = 0; r < 4; ++r) {
        float ls = l[r];
        ls += __shfl_xor(ls, 1); ls += __shfl_xor(ls, 2);
        ls += __shfl_xor(ls, 4); ls += __shfl_xor(ls, 8);
        inv[r] = 1.f / ls;
    }
    #pragma unroll
    for (int c = 0; c < 8; ++c)
        #pragma unroll
        for (int r = 0; r < 4; ++r)
            attn16[(size_t)(grow0 + fq * 4 + r) * H_ + h * HD_ + c * 16 + fr] = (__bf16)(o[c][r] * inv[r]);
}

// ---------------------------------------------------------------- decode attention (separate kernel again)
__global__ __launch_bounds__(256)
void decode_attn_kernel(const __bf16* __restrict__ q16, const __bf16* __restrict__ k16,
                        const __bf16* __restrict__ v16, const float* __restrict__ kc,
                        const float* __restrict__ vc, const int* __restrict__ kv_lens,
                        const float* __restrict__ cost, const float* __restrict__ sint,
                        __bf16* __restrict__ attn16)
{
    const int b = blockIdx.x, h = blockIdx.y;
    const int kvlen = kv_lens[b];
    const int L = kvlen + 1;
    const int tid = threadIdx.x, lane = tid & 63, w = tid >> 6;

    __shared__ float sc_s[LMAX_];
    __shared__ float red[4];
    __shared__ float oacc[HD_];

    const __bf16* qrow = q16 + (size_t)(DOFF_ + b) * H_ + h * HD_;
    const float q1 = (float)qrow[lane], q2 = (float)qrow[lane + 64];
    const __bf16* kdrow = k16 + (size_t)(DOFF_ + b) * H_ + h * HD_;

    for (int l = w; l < L; l += 4) {
        float k1, k2;
        if (l == kvlen) { k1 = (float)kdrow[lane]; k2 = (float)kdrow[lane + 64]; }
        else {
            const float* src = kc + (((size_t)b * LMAX_ + l) * NH_ + h) * HD_;
            k1 = src[lane]; k2 = src[lane + 64];
        }
        const float c = cost[l * 64 + lane], s = sint[l * 64 + lane];
        float d = q1 * (k1 * c - k2 * s) + q2 * (k2 * c + k1 * s);
        #pragma unroll
        for (int off = 1; off < 64; off <<= 1) d += __shfl_xor(d, off);
        if (lane == 0) sc_s[l] = d * SCALE_;
    }
    __syncthreads();

    float mx = -1e30f;
    for (int i = tid; i < L; i += 256) mx = fmaxf(mx, sc_s[i]);
    #pragma unroll
    for (int off = 1; off < 64; off <<= 1) mx = fmaxf(mx, __shfl_xor(mx, off));
    if (lane == 0) red[w] = mx;
    __syncthreads();
    mx = fmaxf(fmaxf(red[0], red[1]), fmaxf(red[2], red[3]));
    __syncthreads();

    float sum = 0.f;
    for (int i = tid; i < L; i += 256) { const float e = __expf(sc_s[i] - mx); sc_s[i] = e; sum += e; }
    #pragma unroll
    for (int off = 1; off < 64; off <<= 1) sum += __shfl_xor(sum, off);
    if (lane == 0) red[w] = sum;
    __syncthreads();
    sum = red[0] + red[1] + red[2] + red[3];
    const float inv = 1.f / sum;

    const int d = tid & 127, team = tid >> 7;
    const __bf16* vdrow = v16 + (size_t)(DOFF_ + b) * H_ + h * HD_;
    float acc = 0.f;
    for (int l = team; l < L; l += 2) {
        float vv;
        if (l == kvlen) vv = (float)vdrow[d];
        else            vv = vc[(((size_t)b * LMAX_ + l) * NH_ + h) * HD_ + d];
        acc += sc_s[l] * vv;
    }
    if (team == 1) oacc[d] = acc;
    __syncthreads();
    if (team == 0) attn16[(size_t)(DOFF_ + b) * H_ + h * HD_ + d] = (__bf16)((acc + oacc[d]) * inv);
}

// ---------------------------------------------------------------- host launch
extern "C" void kernel_launch(void* const* d_in, const int* in_sizes, int n_in,
                              void* d_out, int out_size, void* d_ws, size_t ws_size,
                              hipStream_t stream)
{
    const float* hs     = (const float*)d_in[0];
    const float* wq     = (const float*)d_in[1];
    const float* wk     = (const float*)d_in[2];
    const float* wv     = (const float*)d_in[3];
    const float* wo     = (const float*)d_in[4];
    const float* la_q   = (const float*)d_in[5];
    const float* lb_q   = (const float*)d_in[6];
    const float* la_k   = (const float*)d_in[7];
    const float* lb_k   = (const float*)d_in[8];
    const float* la_v   = (const float*)d_in[9];
    const float* lb_v   = (const float*)d_in[10];
    const float* la_o   = (const float*)d_in[11];
    const float* lb_o   = (const float*)d_in[12];
    const float* kcache = (const float*)d_in[13];
    const float* vcache = (const float*)d_in[14];
    const int*   kvlen  = (const int*)d_in[15];
    float* out = (float*)d_out;

    float*  costab = (float*)d_ws;
    float*  sintab = costab + 1024 * 64;
    __bf16* TMP16  = (__bf16*)(sintab + 1024 * 64);       // [3][MPAD][64]
    __bf16* TMPo16 = TMP16 + (size_t)3 * MPAD_ * 64;      // [MPAD][64]
    __bf16* WB16   = TMPo16 + (size_t)MPAD_ * 64;         // [12288][64]
    __bf16* WBo16  = WB16 + (size_t)3 * H_ * 64;          // [4352][64]
    __bf16* q16    = WBo16 + (size_t)4352 * 64;           // [T][H]
    __bf16* k16    = q16 + (size_t)T_ * H_;
    __bf16* v16    = k16 + (size_t)T_ * H_;
    __bf16* hsb    = v16 + (size_t)T_ * H_;               // [MPAD][H]: hs bf16, later attn16
    __bf16* wT     = hsb + (size_t)MPAD_ * H_;            // [3][H][H]
    __bf16* woT    = wT + (size_t)3 * H_ * H_;            // [H][H]
    __bf16* vT     = woT + (size_t)H_ * H_;               // [H][T]
    __bf16* attn16 = hsb;

    prep1_kernel<<<dim3(T_ + 16384 + 64 + 256), dim3(256), 0, stream>>>(
        hs, hsb, la_q, la_k, la_v, TMP16,
        wq, wk, wv, wo, wT, woT,
        lb_q, lb_k, lb_v, lb_o, WB16, WBo16, costab, sintab);
    gemm_qkv<<<dim3(21, 48), dim3(512), 0, stream>>>(
        hsb, wT, TMP16, WB16, q16, k16, v16, T_);
    post1_kernel<<<dim3(T_ + 1280), dim3(256), 0, stream>>>(
        q16, k16, v16, vT, kvlen, costab, sintab);
    prefill_attn_wave<<<dim3(1280), dim3(256), 0, stream>>>(q16, k16, vT, attn16);
    decode_attn_kernel<<<dim3(DEC_, NH_), dim3(256), 0, stream>>>(q16, k16, v16, kcache, vcache,
                                                                  kvlen, costab, sintab, attn16);
    lora_tmp_bf16_kernel<<<dim3(T_), dim3(256), 0, stream>>>(attn16, la_o, TMPo16);
    gemm_out<<<dim3(11, 22), dim3(512), 0, stream>>>(
        attn16, woT, TMPo16, WBo16, out, T_, H_);
}

// Round 12
// 1064.731 us; speedup vs baseline: 1.0221x; 1.0115x over previous
//
#include <hip/hip_runtime.h>
#include <hip/hip_bf16.h>

// LlamaAttentionWithLora on MI355X — round 12.
// Controlled A/B: exact round-9 launch structure (12 small kernels, proven 942us),
// with ONLY the prefill kernel swapped to the barrier-free per-wave flash variant
// (proven correct in round 11). Everything else byte-identical to round 9.

#define H_    4096
#define NH_   32
#define HD_   128
#define T_    2592
#define DOFF_ 2560
#define DEC_  32
#define LMAX_ 512
#define RANK_ 16
#define MPAD_ 2816

__constant__ float SCALE_ = 0.08838834764831845f; // 128^-0.5

typedef __bf16 bf16x8 __attribute__((ext_vector_type(8)));
typedef __bf16 bf16x4 __attribute__((ext_vector_type(4)));
typedef float  f32x4  __attribute__((ext_vector_type(4)));

__device__ __forceinline__ void async_cp16(const __bf16* g, __bf16* l) {
    __builtin_amdgcn_global_load_lds(
        (const __attribute__((address_space(1))) void*)g,
        (__attribute__((address_space(3))) void*)l, 16, 0, 0);
}

// ---------------------------------------------------------------- hs prep: bf16 convert + lora_tmp fused
__global__ __launch_bounds__(256)
void hs_prep_kernel(const float* __restrict__ X, __bf16* __restrict__ Xb,
                    const float* __restrict__ la0, const float* __restrict__ la1,
                    const float* __restrict__ la2, __bf16* __restrict__ TMP16)
{
    const int r = blockIdx.x;
    const int tid = threadIdx.x;
    const float* xr = X + (size_t)r * H_;
    __bf16* br = Xb + (size_t)r * H_;
    #pragma unroll
    for (int i = 0; i < 4; ++i) {
        float4 v = ((const float4*)xr)[tid + i * 256];
        bf16x4 w; w[0] = (__bf16)v.x; w[1] = (__bf16)v.y; w[2] = (__bf16)v.z; w[3] = (__bf16)v.w;
        ((bf16x4*)br)[tid + i * 256] = w;
    }

    const int si = (r < 648) ? 0 : (r < 1296 ? 1 : (r < 1944 ? 2 : 3));
    const int c    = tid & 15;
    const int part = tid >> 4;
    const float* wa0 = la0 + (size_t)si * H_ * RANK_;
    const float* wa1 = la1 + (size_t)si * H_ * RANK_;
    const float* wa2 = la2 + (size_t)si * H_ * RANK_;
    float s0 = 0.f, s1 = 0.f, s2 = 0.f;
    const int h0 = part * 256;
    for (int h = h0; h < h0 + 256; ++h) {
        const float xv = xr[h];
        s0 += xv * wa0[(size_t)h * RANK_ + c];
        s1 += xv * wa1[(size_t)h * RANK_ + c];
        s2 += xv * wa2[(size_t)h * RANK_ + c];
    }
    __shared__ float red[3][16][17];
    red[0][part][c] = s0; red[1][part][c] = s1; red[2][part][c] = s2;
    __syncthreads();
    if (tid < 192) {
        const int z = tid >> 6, cc = tid & 63;
        float t = 0.f;
        if ((cc >> 4) == si) {
            #pragma unroll
            for (int p = 0; p < 16; ++p) t += red[z][p][cc & 15];
        }
        TMP16[((size_t)z * MPAD_ + r) * 64 + cc] = (__bf16)t;
    }
}

// ---------------------------------------------------------------- f32 [K][N] -> bf16 [N][K], 64x64 tiles
__global__ __launch_bounds__(256)
void transpose_bf16_kernel(const float* __restrict__ W0, const float* __restrict__ W1,
                           const float* __restrict__ W2,
                           __bf16* __restrict__ T0, __bf16* __restrict__ T1, __bf16* __restrict__ T2)
{
    const float* W = (blockIdx.z == 0) ? W0 : (blockIdx.z == 1 ? W1 : W2);
    __bf16* To     = (blockIdx.z == 0) ? T0 : (blockIdx.z == 1 ? T1 : T2);
    __shared__ float s[64][65];
    const int bx = blockIdx.x * 64;
    const int by = blockIdx.y * 64;
    const int tid = threadIdx.x;
    #pragma unroll
    for (int i = 0; i < 4; ++i) {
        const int idx = i * 256 + tid;
        const int r  = idx >> 4;
        const int c4 = (idx & 15) * 4;
        float4 v = *(const float4*)&W[(size_t)(by + r) * H_ + bx + c4];
        s[r][c4] = v.x; s[r][c4 + 1] = v.y; s[r][c4 + 2] = v.z; s[r][c4 + 3] = v.w;
    }
    __syncthreads();
    #pragma unroll
    for (int i = 0; i < 2; ++i) {
        const int idx = i * 256 + tid;
        const int n  = idx >> 3;
        const int kc = (idx & 7) * 8;
        bf16x8 w;
        #pragma unroll
        for (int j = 0; j < 8; ++j) w[j] = (__bf16)s[kc + j][n];
        *(bf16x8*)&To[(size_t)(bx + n) * H_ + by + kc] = w;
    }
}

// ---------------------------------------------------------------- LoRA stage 1 (bf16 X) -> TMPo16[r][64]
__global__ __launch_bounds__(256)
void lora_tmp_bf16_kernel(const __bf16* __restrict__ X,
                          const float* __restrict__ la, __bf16* __restrict__ TMPo16)
{
    const int r = blockIdx.x;
    const int si = (r < 648) ? 0 : (r < 1296 ? 1 : (r < 1944 ? 2 : 3));
    const float* wa = la + (size_t)si * H_ * RANK_;
    const int c    = threadIdx.x & 15;
    const int part = threadIdx.x >> 4;
    const __bf16* xr = X + (size_t)r * H_;
    float s = 0.f;
    const int h0 = part * 256;
    for (int h = h0; h < h0 + 256; ++h) s += (float)xr[h] * wa[(size_t)h * RANK_ + c];
    __shared__ float red[16][17];
    red[part][c] = s;
    __syncthreads();
    if (threadIdx.x < 64) {
        const int cc = threadIdx.x;
        float t = 0.f;
        if ((cc >> 4) == si) {
            #pragma unroll
            for (int p = 0; p < 16; ++p) t += red[p][cc & 15];
        }
        TMPo16[(size_t)r * 64 + cc] = (__bf16)t;
    }
}

// ---------------------------------------------------------------- WB builders
__global__ __launch_bounds__(256)
void wb_build_kernel(const float* __restrict__ lbq, const float* __restrict__ lbk,
                     const float* __restrict__ lbv, const float* __restrict__ lbo,
                     __bf16* __restrict__ WB16, __bf16* __restrict__ WBo16)
{
    const int z = blockIdx.x;
    const int n = blockIdx.y * 256 + threadIdx.x;
    const float* lb = (z == 0) ? lbq : (z == 1 ? lbk : (z == 2 ? lbv : lbo));
    __bf16* dst = (z < 3) ? WB16 + ((size_t)z * H_ + n) * 64 : WBo16 + (size_t)n * 64;
    __bf16 row[64];
    #pragma unroll
    for (int si = 0; si < 4; ++si)
        #pragma unroll
        for (int c = 0; c < 16; ++c)
            row[si * 16 + c] = (__bf16)lb[((size_t)si * 16 + c) * H_ + n];
    #pragma unroll
    for (int i = 0; i < 8; ++i) *(bf16x8*)&dst[i * 8] = *(const bf16x8*)&row[i * 8];
}

// ---------------------------------------------------------------- QKV GEMM (128x256, BK=64, 3-buf ring) + fused lora, bf16 out
__global__ __launch_bounds__(512, 2)
void gemm_qkv(const __bf16* __restrict__ A, const __bf16* __restrict__ Bt,
              const __bf16* __restrict__ TMP16, const __bf16* __restrict__ WB16,
              __bf16* __restrict__ O0, __bf16* __restrict__ O1, __bf16* __restrict__ O2, int M)
{
    const int hw = blockIdx.y * 21 + blockIdx.x;
    const int work = (hw & 7) * 126 + (hw >> 3);     // 1008 = 8 * 126
    const int bm0 = (work % 21) * 128;
    const int bn0 = (work / 21) * 256;

    __shared__ __align__(16) __bf16 Asl[3][128 * 64];
    __shared__ __align__(16) __bf16 Bsl[3][256 * 64];

    const int tid = threadIdx.x, lane = tid & 63, wid = tid >> 6;
    const int wr = wid >> 2, wc = wid & 3;
    const int fr = lane & 15, fq = lane >> 4;

    int arow[2], aoff[2], brow[4], boff[4];
    #pragma unroll
    for (int i = 0; i < 2; ++i) {
        const int ci = i * 512 + tid;
        arow[i] = ci >> 3;
        aoff[i] = ((ci & 7) ^ (arow[i] & 7)) * 8;
    }
    #pragma unroll
    for (int i = 0; i < 4; ++i) {
        const int ci = i * 512 + tid;
        brow[i] = ci >> 3;
        boff[i] = ((ci & 7) ^ (brow[i] & 7)) * 8;
    }
    const __bf16* Ab = A  + (size_t)bm0 * H_;
    const __bf16* Bb = Bt + (size_t)bn0 * H_;

    auto stageA = [&](int buf, int kt2) {
        const int kb = kt2 * 64;
        #pragma unroll
        for (int i = 0; i < 2; ++i)
            async_cp16(Ab + (size_t)arow[i] * H_ + kb + aoff[i],
                       &Asl[buf][(i * 512 + wid * 64) * 8]);
    };
    auto stageB1 = [&](int buf, int kt2) {
        async_cp16(Bb + (size_t)brow[0] * H_ + kt2 * 64 + boff[0],
                   &Bsl[buf][(wid * 64) * 8]);
    };
    auto stageB3 = [&](int buf, int kt2) {
        const int kb = kt2 * 64;
        #pragma unroll
        for (int i = 1; i < 4; ++i)
            async_cp16(Bb + (size_t)brow[i] * H_ + kb + boff[i],
                       &Bsl[buf][(i * 512 + wid * 64) * 8]);
    };
    auto rdA = [&](int buf, int kh, int mi) -> bf16x8 {
        const int row = wr * 64 + mi * 16 + fr;
        const int pc  = (kh * 4 + fq) ^ (row & 7);
        return *(const bf16x8*)&Asl[buf][row * 64 + pc * 8];
    };
    auto rdB = [&](int buf, int kh, int nj) -> bf16x8 {
        const int row = wc * 64 + nj * 16 + fr;
        const int pc  = (kh * 4 + fq) ^ (row & 7);
        return *(const bf16x8*)&Bsl[buf][row * 64 + pc * 8];
    };

    f32x4 acc[4][4] = {};

    stageA(0, 0); stageB1(0, 0); stageB3(0, 0);
    stageA(1, 1); stageB1(1, 1); stageB3(1, 1);
    asm volatile("s_waitcnt vmcnt(6)");
    __builtin_amdgcn_sched_barrier(0);
    __builtin_amdgcn_s_barrier();

    const int NT = H_ / 64;
    int cur = 0, nxt = 2;
    for (int kt = 0; kt < NT; ++kt) {
        const bool pf = (kt + 2 < NT);
        bf16x8 af[4], bfr[4];

        #pragma unroll
        for (int mi = 0; mi < 4; ++mi) af[mi] = rdA(cur, 0, mi);
        #pragma unroll
        for (int nj = 0; nj < 4; ++nj) bfr[nj] = rdB(cur, 0, nj);
        if (pf) { stageA(nxt, kt + 2); stageB1(nxt, kt + 2); }
        __builtin_amdgcn_s_barrier();
        asm volatile("s_waitcnt lgkmcnt(0)");
        __builtin_amdgcn_sched_barrier(0);
        __builtin_amdgcn_s_setprio(1);
        #pragma unroll
        for (int mi = 0; mi < 4; ++mi)
            #pragma unroll
            for (int nj = 0; nj < 4; ++nj)
                acc[mi][nj] = __builtin_amdgcn_mfma_f32_16x16x32_bf16(af[mi], bfr[nj], acc[mi][nj], 0, 0, 0);
        __builtin_amdgcn_s_setprio(0);
        __builtin_amdgcn_s_barrier();

        #pragma unroll
        for (int mi = 0; mi < 4; ++mi) af[mi] = rdA(cur, 1, mi);
        #pragma unroll
        for (int nj = 0; nj < 4; ++nj) bfr[nj] = rdB(cur, 1, nj);
        if (pf) stageB3(nxt, kt + 2);
        __builtin_amdgcn_s_barrier();
        asm volatile("s_waitcnt lgkmcnt(0)");
        __builtin_amdgcn_sched_barrier(0);
        __builtin_amdgcn_s_setprio(1);
        #pragma unroll
        for (int mi = 0; mi < 4; ++mi)
            #pragma unroll
            for (int nj = 0; nj < 4; ++nj)
                acc[mi][nj] = __builtin_amdgcn_mfma_f32_16x16x32_bf16(af[mi], bfr[nj], acc[mi][nj], 0, 0, 0);
        __builtin_amdgcn_s_setprio(0);
        if (pf)               asm volatile("s_waitcnt vmcnt(6)");
        else if (kt + 1 < NT) asm volatile("s_waitcnt vmcnt(0)");
        __builtin_amdgcn_sched_barrier(0);
        __builtin_amdgcn_s_barrier();

        cur = (cur == 2) ? 0 : cur + 1;
        nxt = (nxt == 2) ? 0 : nxt + 1;
    }

    const int colbase = bn0 + wc * 64;
    const int mat = colbase >> 12;
    __bf16* O = (mat == 0) ? O0 : (mat == 1 ? O1 : O2);
    const __bf16* TPm = TMP16 + (size_t)mat * MPAD_ * 64;
    bf16x8 aT[4][2], bW[4][2];
    #pragma unroll
    for (int mi = 0; mi < 4; ++mi)
        #pragma unroll
        for (int kh = 0; kh < 2; ++kh)
            aT[mi][kh] = *(const bf16x8*)&TPm[(size_t)(bm0 + wr * 64 + mi * 16 + fr) * 64 + kh * 32 + fq * 8];
    #pragma unroll
    for (int nj = 0; nj < 4; ++nj)
        #pragma unroll
        for (int kh = 0; kh < 2; ++kh)
            bW[nj][kh] = *(const bf16x8*)&WB16[(size_t)(colbase + nj * 16 + fr) * 64 + kh * 32 + fq * 8];
    #pragma unroll
    for (int mi = 0; mi < 4; ++mi)
        #pragma unroll
        for (int nj = 0; nj < 4; ++nj) {
            acc[mi][nj] = __builtin_amdgcn_mfma_f32_16x16x32_bf16(aT[mi][0], bW[nj][0], acc[mi][nj], 0, 0, 0);
            acc[mi][nj] = __builtin_amdgcn_mfma_f32_16x16x32_bf16(aT[mi][1], bW[nj][1], acc[mi][nj], 0, 0, 0);
        }
    #pragma unroll
    for (int mi = 0; mi < 4; ++mi)
        #pragma unroll
        for (int nj = 0; nj < 4; ++nj) {
            const int cc = (colbase + nj * 16 + fr) & 4095;
            #pragma unroll
            for (int rr = 0; rr < 4; ++rr) {
                const int row = bm0 + wr * 64 + mi * 16 + fq * 4 + rr;
                if (row < M) O[(size_t)row * H_ + cc] = (__bf16)acc[mi][nj][rr];
            }
        }
}

// ---------------------------------------------------------------- O-proj GEMM (256x192, BK=64) + fused lora, f32 out
__global__ __launch_bounds__(512, 2)
void gemm_out(const __bf16* __restrict__ A, const __bf16* __restrict__ Bt,
              const __bf16* __restrict__ TMPo16, const __bf16* __restrict__ WBo16,
              float* __restrict__ C, int M, int Ntot)
{
    const int NY = gridDim.y;
    const int total = gridDim.x * NY;
    const int bid = blockIdx.x * NY + blockIdx.y;
    const int q = total >> 3, r8 = total & 7;
    const int xcd = bid & 7, j = bid >> 3;
    const int swz = (xcd < r8 ? xcd * (q + 1) : r8 * (q + 1) + (xcd - r8) * q) + j;
    const int bm0 = (swz / NY) * 256;
    const int bn0 = (swz % NY) * 192;

    __shared__ __align__(16) __bf16 Asl[2][256 * 64];
    __shared__ __align__(16) __bf16 Bsl[2][192 * 64];

    const int tid = threadIdx.x, lane = tid & 63, wid = tid >> 6;
    const int wr = wid >> 2, wc = wid & 3;
    const int fr = lane & 15, fq = lane >> 4;

    int arow[4], aoff[4], brow[3], boff[3];
    #pragma unroll
    for (int i = 0; i < 4; ++i) {
        const int ci = i * 512 + tid;
        arow[i] = ci >> 3;
        aoff[i] = ((ci & 7) ^ (arow[i] & 7)) * 8;
    }
    #pragma unroll
    for (int i = 0; i < 3; ++i) {
        const int ci = i * 512 + tid;
        brow[i] = ci >> 3;
        boff[i] = ((ci & 7) ^ (brow[i] & 7)) * 8;
    }
    const __bf16* Ab = A  + (size_t)bm0 * H_;
    const __bf16* Bb = Bt + (size_t)bn0 * H_;

    auto stage = [&](int buf, int kt1) {
        const int kb = kt1 * 64;
        #pragma unroll
        for (int i = 0; i < 4; ++i)
            async_cp16(Ab + (size_t)arow[i] * H_ + kb + aoff[i],
                       &Asl[buf][(i * 512 + wid * 64) * 8]);
        #pragma unroll
        for (int i = 0; i < 3; ++i)
            async_cp16(Bb + (size_t)brow[i] * H_ + kb + boff[i],
                       &Bsl[buf][(i * 512 + wid * 64) * 8]);
    };
    auto rdA = [&](int buf, int kh, int mi) -> bf16x8 {
        const int row = wr * 128 + mi * 16 + fr;
        const int kc  = kh * 4 + fq;
        return *(const bf16x8*)&Asl[buf][row * 64 + ((kc ^ (row & 7)) << 3)];
    };
    auto rdB = [&](int buf, int kh, int nj) -> bf16x8 {
        const int row = wc * 48 + nj * 16 + fr;
        const int kc  = kh * 4 + fq;
        return *(const bf16x8*)&Bsl[buf][row * 64 + ((kc ^ (row & 7)) << 3)];
    };

    f32x4 acc[8][3] = {};

    stage(0, 0);
    asm volatile("s_waitcnt vmcnt(0)");
    __builtin_amdgcn_sched_barrier(0);
    __builtin_amdgcn_s_barrier();

    const int NT = H_ / 64;
    for (int kt = 0; kt < NT; ++kt) {
        const int cur = kt & 1, nb = cur ^ 1;
        const bool pf = (kt + 1 < NT);
        bf16x8 af[8], bfr[3];

        #pragma unroll
        for (int mi = 0; mi < 8; ++mi) af[mi] = rdA(cur, 0, mi);
        #pragma unroll
        for (int nj = 0; nj < 3; ++nj) bfr[nj] = rdB(cur, 0, nj);
        if (pf) stage(nb, kt + 1);
        __builtin_amdgcn_s_barrier();
        asm volatile("s_waitcnt lgkmcnt(0)");
        __builtin_amdgcn_sched_barrier(0);
        __builtin_amdgcn_s_setprio(1);
        #pragma unroll
        for (int mi = 0; mi < 8; ++mi)
            #pragma unroll
            for (int nj = 0; nj < 3; ++nj)
                acc[mi][nj] = __builtin_amdgcn_mfma_f32_16x16x32_bf16(af[mi], bfr[nj], acc[mi][nj], 0, 0, 0);
        __builtin_amdgcn_s_setprio(0);
        __builtin_amdgcn_s_barrier();

        #pragma unroll
        for (int mi = 0; mi < 8; ++mi) af[mi] = rdA(cur, 1, mi);
        #pragma unroll
        for (int nj = 0; nj < 3; ++nj) bfr[nj] = rdB(cur, 1, nj);
        __builtin_amdgcn_s_barrier();
        asm volatile("s_waitcnt lgkmcnt(0)");
        __builtin_amdgcn_sched_barrier(0);
        __builtin_amdgcn_s_setprio(1);
        #pragma unroll
        for (int mi = 0; mi < 8; ++mi)
            #pragma unroll
            for (int nj = 0; nj < 3; ++nj)
                acc[mi][nj] = __builtin_amdgcn_mfma_f32_16x16x32_bf16(af[mi], bfr[nj], acc[mi][nj], 0, 0, 0);
        __builtin_amdgcn_s_setprio(0);
        asm volatile("s_waitcnt vmcnt(0)");
        __builtin_amdgcn_sched_barrier(0);
        __builtin_amdgcn_s_barrier();
    }

    const int colw = bn0 + wc * 48;
    bf16x8 aT[8][2], bW[3][2];
    #pragma unroll
    for (int mi = 0; mi < 8; ++mi)
        #pragma unroll
        for (int kh = 0; kh < 2; ++kh)
            aT[mi][kh] = *(const bf16x8*)&TMPo16[(size_t)(bm0 + wr * 128 + mi * 16 + fr) * 64 + kh * 32 + fq * 8];
    #pragma unroll
    for (int nj = 0; nj < 3; ++nj)
        #pragma unroll
        for (int kh = 0; kh < 2; ++kh)
            bW[nj][kh] = *(const bf16x8*)&WBo16[(size_t)(colw + nj * 16 + fr) * 64 + kh * 32 + fq * 8];
    #pragma unroll
    for (int mi = 0; mi < 8; ++mi)
        #pragma unroll
        for (int nj = 0; nj < 3; ++nj) {
            acc[mi][nj] = __builtin_amdgcn_mfma_f32_16x16x32_bf16(aT[mi][0], bW[nj][0], acc[mi][nj], 0, 0, 0);
            acc[mi][nj] = __builtin_amdgcn_mfma_f32_16x16x32_bf16(aT[mi][1], bW[nj][1], acc[mi][nj], 0, 0, 0);
        }
    #pragma unroll
    for (int mi = 0; mi < 8; ++mi)
        #pragma unroll
        for (int nj = 0; nj < 3; ++nj) {
            const int col = colw + nj * 16 + fr;
            if (col < Ntot) {
                #pragma unroll
                for (int rr = 0; rr < 4; ++rr) {
                    const int row = bm0 + wr * 128 + mi * 16 + fq * 4 + rr;
                    if (row < M) C[(size_t)row * H_ + col] = acc[mi][nj][rr];
                }
            }
        }
}

// ---------------------------------------------------------------- RoPE tables
__global__ void rope_table_kernel(float* __restrict__ cost, float* __restrict__ sint)
{
    const int p = blockIdx.x;
    const int i = threadIdx.x;
    const float inv = powf(10000.f, -(float)(2 * i) / (float)HD_);
    const float a = (float)p * inv;
    cost[p * 64 + i] = cosf(a);
    sint[p * 64 + i] = sinf(a);
}

// ---------------------------------------------------------------- rope16
__global__ __launch_bounds__(256)
void rope16_kernel(__bf16* __restrict__ q16, __bf16* __restrict__ k16,
                   const int* __restrict__ kv_lens,
                   const float* __restrict__ cost, const float* __restrict__ sint)
{
    const int r = blockIdx.x;
    int pos; bool dok;
    if (r < DOFF_) {
        if      (r < 1024) pos = r;
        else if (r < 1536) pos = r - 1024;
        else if (r < 2304) pos = r - 1536;
        else               pos = r - 2304;
        dok = true;
    } else {
        pos = kv_lens[r - DOFF_];
        dok = false;
    }
    const int tid = threadIdx.x;
    const int h = tid >> 3, sub = tid & 7;
    const int i0 = sub * 8;
    const size_t b1 = (size_t)r * H_ + h * HD_ + i0;
    const size_t b2 = b1 + 64;

    float cs[8], sn[8];
    #pragma unroll
    for (int j = 0; j < 8; ++j) { cs[j] = cost[pos * 64 + i0 + j]; sn[j] = sint[pos * 64 + i0 + j]; }

    {
        bf16x8 x1 = *(const bf16x8*)&q16[b1], x2 = *(const bf16x8*)&q16[b2];
        bf16x8 o1, o2;
        #pragma unroll
        for (int j = 0; j < 8; ++j) {
            const float f1 = (float)x1[j], f2 = (float)x2[j];
            o1[j] = (__bf16)(f1 * cs[j] - f2 * sn[j]);
            o2[j] = (__bf16)(f2 * cs[j] + f1 * sn[j]);
        }
        *(bf16x8*)&q16[b1] = o1; *(bf16x8*)&q16[b2] = o2;
    }
    if (dok) {
        bf16x8 x1 = *(const bf16x8*)&k16[b1], x2 = *(const bf16x8*)&k16[b2];
        bf16x8 o1, o2;
        #pragma unroll
        for (int j = 0; j < 8; ++j) {
            const float f1 = (float)x1[j], f2 = (float)x2[j];
            o1[j] = (__bf16)(f1 * cs[j] - f2 * sn[j]);
            o2[j] = (__bf16)(f2 * cs[j] + f1 * sn[j]);
        }
        *(bf16x8*)&k16[b1] = o1; *(bf16x8*)&k16[b2] = o2;
    }
}

// ---------------------------------------------------------------- V transpose per head (bf16 in)
__global__ __launch_bounds__(256)
void transpose_v_kernel(const __bf16* __restrict__ v16, __bf16* __restrict__ vT)
{
    __shared__ __bf16 s[64][136];
    const int tb = blockIdx.x;
    const int h  = blockIdx.y;
    const int tid = threadIdx.x;
    #pragma unroll
    for (int i = 0; i < 4; ++i) {
        const int idx = i * 256 + tid;
        const int row = idx >> 4;
        const int c8  = (idx & 15) * 8;
        *(bf16x8*)&s[row][c8] = *(const bf16x8*)&v16[(size_t)(tb * 64 + row) * H_ + h * HD_ + c8];
    }
    __syncthreads();
    #pragma unroll
    for (int i = 0; i < 4; ++i) {
        const int idx = i * 256 + tid;
        const int d = idx >> 3;
        const int c = idx & 7;
        bf16x8 w;
        #pragma unroll
        for (int j = 0; j < 8; ++j) w[j] = s[c * 8 + j][d];
        *(bf16x8*)&vT[(size_t)(h * HD_ + d) * T_ + tb * 64 + c * 8] = w;
    }
}

// ---------------------------------------------------------------- prefill attention: barrier-free per-wave flash
// wave = (16 q-rows, head). KVBLK=32. K/V^T fragments read directly from global/L2.
// LDS only: per-wave 1KB P buffer. No block barriers.
__global__ __launch_bounds__(256)
void prefill_attn_wave(const __bf16* __restrict__ q16, const __bf16* __restrict__ k16,
                       const __bf16* __restrict__ vT, __bf16* __restrict__ attn16)
{
    const int tid = threadIdx.x, lane = tid & 63, wid = tid >> 6;
    const int h = blockIdx.x / 40;
    const int g = (blockIdx.x % 40) * 4 + wid;     // 0..159 q-block16 index
    int soff, gq;
    if      (g < 64)  { soff = 0;    gq = g; }
    else if (g < 96)  { soff = 1024; gq = g - 64; }
    else if (g < 144) { soff = 1536; gq = g - 96; }
    else              { soff = 2304; gq = g - 144; }
    const int qoff = gq * 16;
    const int fr = lane & 15, fq = lane >> 4;

    __shared__ __align__(16) __bf16 Pl[4][16 * 32];
    __bf16* Plw = Pl[wid];

    const int grow0 = soff + qoff;
    bf16x8 qf[4];
    #pragma unroll
    for (int ks = 0; ks < 4; ++ks)
        qf[ks] = *(const bf16x8*)&q16[(size_t)(grow0 + fr) * H_ + h * HD_ + ks * 32 + fq * 8];

    float m[4], l[4];
    #pragma unroll
    for (int r = 0; r < 4; ++r) { m[r] = -1e30f; l[r] = 0.f; }
    f32x4 o[8] = {};

    const int ntiles = (qoff + 15) / 32 + 1;
    const __bf16* Kb = k16 + h * HD_;
    const __bf16* Vb = vT + (size_t)h * HD_ * T_;

    for (int t = 0; t < ntiles; ++t) {
        const int kt = t * 32;

        f32x4 s[2] = {};
        #pragma unroll
        for (int sub = 0; sub < 2; ++sub)
            #pragma unroll
            for (int ks = 0; ks < 4; ++ks) {
                bf16x8 bk = *(const bf16x8*)&Kb[(size_t)(soff + kt + sub * 16 + fr) * H_ + ks * 32 + fq * 8];
                s[sub] = __builtin_amdgcn_mfma_f32_16x16x32_bf16(qf[ks], bk, s[sub], 0, 0, 0);
            }

        float p[2][4];
        #pragma unroll
        for (int sub = 0; sub < 2; ++sub)
            #pragma unroll
            for (int r = 0; r < 4; ++r) {
                const int qpos = qoff + fq * 4 + r;
                const int kpos = kt + sub * 16 + fr;
                p[sub][r] = (kpos <= qpos) ? s[sub][r] * SCALE_ : -1e30f;
            }
        float tm2[4];
        #pragma unroll
        for (int r = 0; r < 4; ++r) {
            float tm = fmaxf(p[0][r], p[1][r]);
            tm = fmaxf(tm, __shfl_xor(tm, 1));
            tm = fmaxf(tm, __shfl_xor(tm, 2));
            tm = fmaxf(tm, __shfl_xor(tm, 4));
            tm = fmaxf(tm, __shfl_xor(tm, 8));
            tm2[r] = tm;
        }
        bool need = false;
        #pragma unroll
        for (int r = 0; r < 4; ++r) need |= (tm2[r] > m[r] + 8.f);
        if (__any(need)) {
            #pragma unroll
            for (int r = 0; r < 4; ++r) {
                const float mn = fmaxf(m[r], tm2[r]);
                const float f  = __expf(m[r] - mn);
                m[r] = mn;
                l[r] *= f;
                #pragma unroll
                for (int c = 0; c < 8; ++c) o[c][r] *= f;
            }
        }
        #pragma unroll
        for (int r = 0; r < 4; ++r) {
            float ls = 0.f;
            #pragma unroll
            for (int sub = 0; sub < 2; ++sub) {
                p[sub][r] = __expf(p[sub][r] - m[r]);
                ls += p[sub][r];
            }
            l[r] += ls;
        }

        #pragma unroll
        for (int sub = 0; sub < 2; ++sub)
            #pragma unroll
            for (int r = 0; r < 4; ++r) {
                const int qr = fq * 4 + r;
                const int col = sub * 16 + fr;
                Plw[qr * 32 + ((((col >> 3) ^ (qr & 3)) & 3) * 8) + (col & 7)] = (__bf16)p[sub][r];
            }
        bf16x8 pa = *(const bf16x8*)&Plw[fr * 32 + (((fq ^ (fr & 3)) & 3) * 8)];

        #pragma unroll
        for (int c = 0; c < 8; ++c) {
            bf16x8 bv = *(const bf16x8*)&Vb[(size_t)(c * 16 + fr) * T_ + soff + kt + fq * 8];
            o[c] = __builtin_amdgcn_mfma_f32_16x16x32_bf16(pa, bv, o[c], 0, 0, 0);
        }
    }

    float inv[4];
    #pragma unroll
    for (int r = 0; r < 4; ++r) {
        float ls = l[r];
        ls += __shfl_xor(ls, 1); ls += __shfl_xor(ls, 2);
        ls += __shfl_xor(ls, 4); ls += __shfl_xor(ls, 8);
        inv[r] = 1.f / ls;
    }
    #pragma unroll
    for (int c = 0; c < 8; ++c)
        #pragma unroll
        for (int r = 0; r < 4; ++r)
            attn16[(size_t)(grow0 + fq * 4 + r) * H_ + h * HD_ + c * 16 + fr] = (__bf16)(o[c][r] * inv[r]);
}

// ---------------------------------------------------------------- decode attention
__global__ __launch_bounds__(256)
void decode_attn_kernel(const __bf16* __restrict__ q16, const __bf16* __restrict__ k16,
                        const __bf16* __restrict__ v16, const float* __restrict__ kc,
                        const float* __restrict__ vc, const int* __restrict__ kv_lens,
                        const float* __restrict__ cost, const float* __restrict__ sint,
                        __bf16* __restrict__ attn16)
{
    const int b = blockIdx.x, h = blockIdx.y;
    const int kvlen = kv_lens[b];
    const int L = kvlen + 1;
    const int tid = threadIdx.x, lane = tid & 63, w = tid >> 6;

    __shared__ float sc_s[LMAX_];
    __shared__ float red[4];
    __shared__ float oacc[HD_];

    const __bf16* qrow = q16 + (size_t)(DOFF_ + b) * H_ + h * HD_;
    const float q1 = (float)qrow[lane], q2 = (float)qrow[lane + 64];
    const __bf16* kdrow = k16 + (size_t)(DOFF_ + b) * H_ + h * HD_;

    for (int l = w; l < L; l += 4) {
        float k1, k2;
        if (l == kvlen) { k1 = (float)kdrow[lane]; k2 = (float)kdrow[lane + 64]; }
        else {
            const float* src = kc + (((size_t)b * LMAX_ + l) * NH_ + h) * HD_;
            k1 = src[lane]; k2 = src[lane + 64];
        }
        const float c = cost[l * 64 + lane], s = sint[l * 64 + lane];
        float d = q1 * (k1 * c - k2 * s) + q2 * (k2 * c + k1 * s);
        #pragma unroll
        for (int off = 1; off < 64; off <<= 1) d += __shfl_xor(d, off);
        if (lane == 0) sc_s[l] = d * SCALE_;
    }
    __syncthreads();

    float mx = -1e30f;
    for (int i = tid; i < L; i += 256) mx = fmaxf(mx, sc_s[i]);
    #pragma unroll
    for (int off = 1; off < 64; off <<= 1) mx = fmaxf(mx, __shfl_xor(mx, off));
    if (lane == 0) red[w] = mx;
    __syncthreads();
    mx = fmaxf(fmaxf(red[0], red[1]), fmaxf(red[2], red[3]));
    __syncthreads();

    float sum = 0.f;
    for (int i = tid; i < L; i += 256) { const float e = __expf(sc_s[i] - mx); sc_s[i] = e; sum += e; }
    #pragma unroll
    for (int off = 1; off < 64; off <<= 1) sum += __shfl_xor(sum, off);
    if (lane == 0) red[w] = sum;
    __syncthreads();
    sum = red[0] + red[1] + red[2] + red[3];
    const float inv = 1.f / sum;

    const int d = tid & 127, team = tid >> 7;
    const __bf16* vdrow = v16 + (size_t)(DOFF_ + b) * H_ + h * HD_;
    float acc = 0.f;
    for (int l = team; l < L; l += 2) {
        float vv;
        if (l == kvlen) vv = (float)vdrow[d];
        else            vv = vc[(((size_t)b * LMAX_ + l) * NH_ + h) * HD_ + d];
        acc += sc_s[l] * vv;
    }
    if (team == 1) oacc[d] = acc;
    __syncthreads();
    if (team == 0) attn16[(size_t)(DOFF_ + b) * H_ + h * HD_ + d] = (__bf16)((acc + oacc[d]) * inv);
}

// ---------------------------------------------------------------- host launch
extern "C" void kernel_launch(void* const* d_in, const int* in_sizes, int n_in,
                              void* d_out, int out_size, void* d_ws, size_t ws_size,
                              hipStream_t stream)
{
    const float* hs     = (const float*)d_in[0];
    const float* wq     = (const float*)d_in[1];
    const float* wk     = (const float*)d_in[2];
    const float* wv     = (const float*)d_in[3];
    const float* wo     = (const float*)d_in[4];
    const float* la_q   = (const float*)d_in[5];
    const float* lb_q   = (const float*)d_in[6];
    const float* la_k   = (const float*)d_in[7];
    const float* lb_k   = (const float*)d_in[8];
    const float* la_v   = (const float*)d_in[9];
    const float* lb_v   = (const float*)d_in[10];
    const float* la_o   = (const float*)d_in[11];
    const float* lb_o   = (const float*)d_in[12];
    const float* kcache = (const float*)d_in[13];
    const float* vcache = (const float*)d_in[14];
    const int*   kvlen  = (const int*)d_in[15];
    float* out = (float*)d_out;

    float*  costab = (float*)d_ws;
    float*  sintab = costab + 1024 * 64;
    __bf16* TMP16  = (__bf16*)(sintab + 1024 * 64);       // [3][MPAD][64]
    __bf16* TMPo16 = TMP16 + (size_t)3 * MPAD_ * 64;      // [MPAD][64]
    __bf16* WB16   = TMPo16 + (size_t)MPAD_ * 64;         // [12288][64]
    __bf16* WBo16  = WB16 + (size_t)3 * H_ * 64;          // [4352][64]
    __bf16* q16    = WBo16 + (size_t)4352 * 64;           // [T][H]
    __bf16* k16    = q16 + (size_t)T_ * H_;
    __bf16* v16    = k16 + (size_t)T_ * H_;
    __bf16* hsb    = v16 + (size_t)T_ * H_;               // [MPAD][H]: hs bf16, later attn16
    __bf16* wT     = hsb + (size_t)MPAD_ * H_;            // [3][H][H]
    __bf16* vT     = wT + (size_t)H_ * H_;                // reuse wk^T slot after QKV GEMM
    __bf16* attn16 = hsb;

    rope_table_kernel<<<dim3(1024), dim3(64), 0, stream>>>(costab, sintab);
    hs_prep_kernel<<<dim3(T_), dim3(256), 0, stream>>>(hs, hsb, la_q, la_k, la_v, TMP16);
    transpose_bf16_kernel<<<dim3(64, 64, 3), dim3(256), 0, stream>>>(
        wq, wk, wv, wT, wT + (size_t)H_ * H_, wT + (size_t)2 * H_ * H_);
    wb_build_kernel<<<dim3(4, 16), dim3(256), 0, stream>>>(lb_q, lb_k, lb_v, lb_o, WB16, WBo16);
    gemm_qkv<<<dim3(21, 48), dim3(512), 0, stream>>>(
        hsb, wT, TMP16, WB16, q16, k16, v16, T_);
    rope16_kernel<<<dim3(T_), dim3(256), 0, stream>>>(q16, k16, kvlen, costab, sintab);
    transpose_v_kernel<<<dim3(40, 32), dim3(256), 0, stream>>>(v16, vT);
    prefill_attn_wave<<<dim3(1280), dim3(256), 0, stream>>>(q16, k16, vT, attn16);
    decode_attn_kernel<<<dim3(DEC_, NH_), dim3(256), 0, stream>>>(q16, k16, v16, kcache, vcache,
                                                                  kvlen, costab, sintab, attn16);
    transpose_bf16_kernel<<<dim3(64, 64, 1), dim3(256), 0, stream>>>(wo, wo, wo, wT, wT, wT);
    lora_tmp_bf16_kernel<<<dim3(T_), dim3(256), 0, stream>>>(attn16, la_o, TMPo16);
    gemm_out<<<dim3(11, 22), dim3(512), 0, stream>>>(
        attn16, wT, TMPo16, WBo16, out, T_, H_);
}

// Round 13
// 897.858 us; speedup vs baseline: 1.2120x; 1.1859x over previous
//
#include <hip/hip_runtime.h>
#include <hip/hip_bf16.h>

// LlamaAttentionWithLora on MI355X — round 13.
// Exact round-9 structure (best: 942us) + two contained edits:
// (1) prefill LPT heavy-first block ordering (pure permutation of qb),
// (2) hs_prep stages x in LDS for the LoRA dot (kills 256 broadcast global loads/thread).

#define H_    4096
#define NH_   32
#define HD_   128
#define T_    2592
#define DOFF_ 2560
#define DEC_  32
#define LMAX_ 512
#define RANK_ 16
#define MPAD_ 2816

__constant__ float SCALE_ = 0.08838834764831845f; // 128^-0.5

typedef __bf16 bf16x8 __attribute__((ext_vector_type(8)));
typedef __bf16 bf16x4 __attribute__((ext_vector_type(4)));
typedef float  f32x4  __attribute__((ext_vector_type(4)));

__device__ __forceinline__ void async_cp16(const __bf16* g, __bf16* l) {
    __builtin_amdgcn_global_load_lds(
        (const __attribute__((address_space(1))) void*)g,
        (__attribute__((address_space(3))) void*)l, 16, 0, 0);
}

// heavy-first (LPT) order of prefill q-blocks, by descending K-tile count
__constant__ int QBORD_[40] = {15,14,13,12,11,35,10,34,9,33,8,32,7,23,31,6,22,30,
                               5,21,29,4,20,28,3,19,27,39,2,18,26,38,1,17,25,37,0,16,24,36};

// ---------------------------------------------------------------- hs prep: bf16 convert + lora_tmp (x via LDS)
__global__ __launch_bounds__(256)
void hs_prep_kernel(const float* __restrict__ X, __bf16* __restrict__ Xb,
                    const float* __restrict__ la0, const float* __restrict__ la1,
                    const float* __restrict__ la2, __bf16* __restrict__ TMP16)
{
    const int r = blockIdx.x;
    const int tid = threadIdx.x;
    const float* xr = X + (size_t)r * H_;
    __bf16* br = Xb + (size_t)r * H_;

    __shared__ float xs[H_ / 1];  // 4096 floats = 16KB
    #pragma unroll
    for (int i = 0; i < 4; ++i) {
        float4 v = ((const float4*)xr)[tid + i * 256];
        bf16x4 w; w[0] = (__bf16)v.x; w[1] = (__bf16)v.y; w[2] = (__bf16)v.z; w[3] = (__bf16)v.w;
        ((bf16x4*)br)[tid + i * 256] = w;
        *(float4*)&xs[(tid + i * 256) * 4] = v;
    }
    __syncthreads();

    const int si = (r < 648) ? 0 : (r < 1296 ? 1 : (r < 1944 ? 2 : 3));
    const int c    = tid & 15;
    const int part = tid >> 4;
    const float* wa0 = la0 + (size_t)si * H_ * RANK_;
    const float* wa1 = la1 + (size_t)si * H_ * RANK_;
    const float* wa2 = la2 + (size_t)si * H_ * RANK_;
    float s0 = 0.f, s1 = 0.f, s2 = 0.f;
    const int h0 = part * 256;
    for (int h = h0; h < h0 + 256; ++h) {
        const float xv = xs[h];
        s0 += xv * wa0[(size_t)h * RANK_ + c];
        s1 += xv * wa1[(size_t)h * RANK_ + c];
        s2 += xv * wa2[(size_t)h * RANK_ + c];
    }
    __shared__ float red[3][16][17];
    red[0][part][c] = s0; red[1][part][c] = s1; red[2][part][c] = s2;
    __syncthreads();
    if (tid < 192) {
        const int z = tid >> 6, cc = tid & 63;
        float t = 0.f;
        if ((cc >> 4) == si) {
            #pragma unroll
            for (int p = 0; p < 16; ++p) t += red[z][p][cc & 15];
        }
        TMP16[((size_t)z * MPAD_ + r) * 64 + cc] = (__bf16)t;
    }
}

// ---------------------------------------------------------------- f32 [K][N] -> bf16 [N][K], 64x64 tiles
__global__ __launch_bounds__(256)
void transpose_bf16_kernel(const float* __restrict__ W0, const float* __restrict__ W1,
                           const float* __restrict__ W2,
                           __bf16* __restrict__ T0, __bf16* __restrict__ T1, __bf16* __restrict__ T2)
{
    const float* W = (blockIdx.z == 0) ? W0 : (blockIdx.z == 1 ? W1 : W2);
    __bf16* To     = (blockIdx.z == 0) ? T0 : (blockIdx.z == 1 ? T1 : T2);
    __shared__ float s[64][65];
    const int bx = blockIdx.x * 64;
    const int by = blockIdx.y * 64;
    const int tid = threadIdx.x;
    #pragma unroll
    for (int i = 0; i < 4; ++i) {
        const int idx = i * 256 + tid;
        const int r  = idx >> 4;
        const int c4 = (idx & 15) * 4;
        float4 v = *(const float4*)&W[(size_t)(by + r) * H_ + bx + c4];
        s[r][c4] = v.x; s[r][c4 + 1] = v.y; s[r][c4 + 2] = v.z; s[r][c4 + 3] = v.w;
    }
    __syncthreads();
    #pragma unroll
    for (int i = 0; i < 2; ++i) {
        const int idx = i * 256 + tid;
        const int n  = idx >> 3;
        const int kc = (idx & 7) * 8;
        bf16x8 w;
        #pragma unroll
        for (int j = 0; j < 8; ++j) w[j] = (__bf16)s[kc + j][n];
        *(bf16x8*)&To[(size_t)(bx + n) * H_ + by + kc] = w;
    }
}

// ---------------------------------------------------------------- LoRA stage 1 (bf16 X) -> TMPo16[r][64]
__global__ __launch_bounds__(256)
void lora_tmp_bf16_kernel(const __bf16* __restrict__ X,
                          const float* __restrict__ la, __bf16* __restrict__ TMPo16)
{
    const int r = blockIdx.x;
    const int si = (r < 648) ? 0 : (r < 1296 ? 1 : (r < 1944 ? 2 : 3));
    const float* wa = la + (size_t)si * H_ * RANK_;
    const int c    = threadIdx.x & 15;
    const int part = threadIdx.x >> 4;
    const __bf16* xr = X + (size_t)r * H_;
    float s = 0.f;
    const int h0 = part * 256;
    for (int h = h0; h < h0 + 256; ++h) s += (float)xr[h] * wa[(size_t)h * RANK_ + c];
    __shared__ float red[16][17];
    red[part][c] = s;
    __syncthreads();
    if (threadIdx.x < 64) {
        const int cc = threadIdx.x;
        float t = 0.f;
        if ((cc >> 4) == si) {
            #pragma unroll
            for (int p = 0; p < 16; ++p) t += red[p][cc & 15];
        }
        TMPo16[(size_t)r * 64 + cc] = (__bf16)t;
    }
}

// ---------------------------------------------------------------- WB builders
__global__ __launch_bounds__(256)
void wb_build_kernel(const float* __restrict__ lbq, const float* __restrict__ lbk,
                     const float* __restrict__ lbv, const float* __restrict__ lbo,
                     __bf16* __restrict__ WB16, __bf16* __restrict__ WBo16)
{
    const int z = blockIdx.x;
    const int n = blockIdx.y * 256 + threadIdx.x;
    const float* lb = (z == 0) ? lbq : (z == 1 ? lbk : (z == 2 ? lbv : lbo));
    __bf16* dst = (z < 3) ? WB16 + ((size_t)z * H_ + n) * 64 : WBo16 + (size_t)n * 64;
    __bf16 row[64];
    #pragma unroll
    for (int si = 0; si < 4; ++si)
        #pragma unroll
        for (int c = 0; c < 16; ++c)
            row[si * 16 + c] = (__bf16)lb[((size_t)si * 16 + c) * H_ + n];
    #pragma unroll
    for (int i = 0; i < 8; ++i) *(bf16x8*)&dst[i * 8] = *(const bf16x8*)&row[i * 8];
}

// ---------------------------------------------------------------- QKV GEMM (128x256, BK=64, 3-buf ring) + fused lora, bf16 out
__global__ __launch_bounds__(512, 2)
void gemm_qkv(const __bf16* __restrict__ A, const __bf16* __restrict__ Bt,
              const __bf16* __restrict__ TMP16, const __bf16* __restrict__ WB16,
              __bf16* __restrict__ O0, __bf16* __restrict__ O1, __bf16* __restrict__ O2, int M)
{
    const int hw = blockIdx.y * 21 + blockIdx.x;
    const int work = (hw & 7) * 126 + (hw >> 3);     // 1008 = 8 * 126
    const int bm0 = (work % 21) * 128;
    const int bn0 = (work / 21) * 256;

    __shared__ __align__(16) __bf16 Asl[3][128 * 64];
    __shared__ __align__(16) __bf16 Bsl[3][256 * 64];

    const int tid = threadIdx.x, lane = tid & 63, wid = tid >> 6;
    const int wr = wid >> 2, wc = wid & 3;
    const int fr = lane & 15, fq = lane >> 4;

    int arow[2], aoff[2], brow[4], boff[4];
    #pragma unroll
    for (int i = 0; i < 2; ++i) {
        const int ci = i * 512 + tid;
        arow[i] = ci >> 3;
        aoff[i] = ((ci & 7) ^ (arow[i] & 7)) * 8;
    }
    #pragma unroll
    for (int i = 0; i < 4; ++i) {
        const int ci = i * 512 + tid;
        brow[i] = ci >> 3;
        boff[i] = ((ci & 7) ^ (brow[i] & 7)) * 8;
    }
    const __bf16* Ab = A  + (size_t)bm0 * H_;
    const __bf16* Bb = Bt + (size_t)bn0 * H_;

    auto stageA = [&](int buf, int kt2) {
        const int kb = kt2 * 64;
        #pragma unroll
        for (int i = 0; i < 2; ++i)
            async_cp16(Ab + (size_t)arow[i] * H_ + kb + aoff[i],
                       &Asl[buf][(i * 512 + wid * 64) * 8]);
    };
    auto stageB1 = [&](int buf, int kt2) {
        async_cp16(Bb + (size_t)brow[0] * H_ + kt2 * 64 + boff[0],
                   &Bsl[buf][(wid * 64) * 8]);
    };
    auto stageB3 = [&](int buf, int kt2) {
        const int kb = kt2 * 64;
        #pragma unroll
        for (int i = 1; i < 4; ++i)
            async_cp16(Bb + (size_t)brow[i] * H_ + kb + boff[i],
                       &Bsl[buf][(i * 512 + wid * 64) * 8]);
    };
    auto rdA = [&](int buf, int kh, int mi) -> bf16x8 {
        const int row = wr * 64 + mi * 16 + fr;
        const int pc  = (kh * 4 + fq) ^ (row & 7);
        return *(const bf16x8*)&Asl[buf][row * 64 + pc * 8];
    };
    auto rdB = [&](int buf, int kh, int nj) -> bf16x8 {
        const int row = wc * 64 + nj * 16 + fr;
        const int pc  = (kh * 4 + fq) ^ (row & 7);
        return *(const bf16x8*)&Bsl[buf][row * 64 + pc * 8];
    };

    f32x4 acc[4][4] = {};

    stageA(0, 0); stageB1(0, 0); stageB3(0, 0);
    stageA(1, 1); stageB1(1, 1); stageB3(1, 1);
    asm volatile("s_waitcnt vmcnt(6)");
    __builtin_amdgcn_sched_barrier(0);
    __builtin_amdgcn_s_barrier();

    const int NT = H_ / 64;
    int cur = 0, nxt = 2;
    for (int kt = 0; kt < NT; ++kt) {
        const bool pf = (kt + 2 < NT);
        bf16x8 af[4], bfr[4];

        #pragma unroll
        for (int mi = 0; mi < 4; ++mi) af[mi] = rdA(cur, 0, mi);
        #pragma unroll
        for (int nj = 0; nj < 4; ++nj) bfr[nj] = rdB(cur, 0, nj);
        if (pf) { stageA(nxt, kt + 2); stageB1(nxt, kt + 2); }
        __builtin_amdgcn_s_barrier();
        asm volatile("s_waitcnt lgkmcnt(0)");
        __builtin_amdgcn_sched_barrier(0);
        __builtin_amdgcn_s_setprio(1);
        #pragma unroll
        for (int mi = 0; mi < 4; ++mi)
            #pragma unroll
            for (int nj = 0; nj < 4; ++nj)
                acc[mi][nj] = __builtin_amdgcn_mfma_f32_16x16x32_bf16(af[mi], bfr[nj], acc[mi][nj], 0, 0, 0);
        __builtin_amdgcn_s_setprio(0);
        __builtin_amdgcn_s_barrier();

        #pragma unroll
        for (int mi = 0; mi < 4; ++mi) af[mi] = rdA(cur, 1, mi);
        #pragma unroll
        for (int nj = 0; nj < 4; ++nj) bfr[nj] = rdB(cur, 1, nj);
        if (pf) stageB3(nxt, kt + 2);
        __builtin_amdgcn_s_barrier();
        asm volatile("s_waitcnt lgkmcnt(0)");
        __builtin_amdgcn_sched_barrier(0);
        __builtin_amdgcn_s_setprio(1);
        #pragma unroll
        for (int mi = 0; mi < 4; ++mi)
            #pragma unroll
            for (int nj = 0; nj < 4; ++nj)
                acc[mi][nj] = __builtin_amdgcn_mfma_f32_16x16x32_bf16(af[mi], bfr[nj], acc[mi][nj], 0, 0, 0);
        __builtin_amdgcn_s_setprio(0);
        if (pf)               asm volatile("s_waitcnt vmcnt(6)");
        else if (kt + 1 < NT) asm volatile("s_waitcnt vmcnt(0)");
        __builtin_amdgcn_sched_barrier(0);
        __builtin_amdgcn_s_barrier();

        cur = (cur == 2) ? 0 : cur + 1;
        nxt = (nxt == 2) ? 0 : nxt + 1;
    }

    const int colbase = bn0 + wc * 64;
    const int mat = colbase >> 12;
    __bf16* O = (mat == 0) ? O0 : (mat == 1 ? O1 : O2);
    const __bf16* TPm = TMP16 + (size_t)mat * MPAD_ * 64;
    bf16x8 aT[4][2], bW[4][2];
    #pragma unroll
    for (int mi = 0; mi < 4; ++mi)
        #pragma unroll
        for (int kh = 0; kh < 2; ++kh)
            aT[mi][kh] = *(const bf16x8*)&TPm[(size_t)(bm0 + wr * 64 + mi * 16 + fr) * 64 + kh * 32 + fq * 8];
    #pragma unroll
    for (int nj = 0; nj < 4; ++nj)
        #pragma unroll
        for (int kh = 0; kh < 2; ++kh)
            bW[nj][kh] = *(const bf16x8*)&WB16[(size_t)(colbase + nj * 16 + fr) * 64 + kh * 32 + fq * 8];
    #pragma unroll
    for (int mi = 0; mi < 4; ++mi)
        #pragma unroll
        for (int nj = 0; nj < 4; ++nj) {
            acc[mi][nj] = __builtin_amdgcn_mfma_f32_16x16x32_bf16(aT[mi][0], bW[nj][0], acc[mi][nj], 0, 0, 0);
            acc[mi][nj] = __builtin_amdgcn_mfma_f32_16x16x32_bf16(aT[mi][1], bW[nj][1], acc[mi][nj], 0, 0, 0);
        }
    #pragma unroll
    for (int mi = 0; mi < 4; ++mi)
        #pragma unroll
        for (int nj = 0; nj < 4; ++nj) {
            const int cc = (colbase + nj * 16 + fr) & 4095;
            #pragma unroll
            for (int rr = 0; rr < 4; ++rr) {
                const int row = bm0 + wr * 64 + mi * 16 + fq * 4 + rr;
                if (row < M) O[(size_t)row * H_ + cc] = (__bf16)acc[mi][nj][rr];
            }
        }
}

// ---------------------------------------------------------------- O-proj GEMM (256x192, BK=64) + fused lora, f32 out
__global__ __launch_bounds__(512, 2)
void gemm_out(const __bf16* __restrict__ A, const __bf16* __restrict__ Bt,
              const __bf16* __restrict__ TMPo16, const __bf16* __restrict__ WBo16,
              float* __restrict__ C, int M, int Ntot)
{
    const int NY = gridDim.y;
    const int total = gridDim.x * NY;
    const int bid = blockIdx.x * NY + blockIdx.y;
    const int q = total >> 3, r8 = total & 7;
    const int xcd = bid & 7, j = bid >> 3;
    const int swz = (xcd < r8 ? xcd * (q + 1) : r8 * (q + 1) + (xcd - r8) * q) + j;
    const int bm0 = (swz / NY) * 256;
    const int bn0 = (swz % NY) * 192;

    __shared__ __align__(16) __bf16 Asl[2][256 * 64];
    __shared__ __align__(16) __bf16 Bsl[2][192 * 64];

    const int tid = threadIdx.x, lane = tid & 63, wid = tid >> 6;
    const int wr = wid >> 2, wc = wid & 3;
    const int fr = lane & 15, fq = lane >> 4;

    int arow[4], aoff[4], brow[3], boff[3];
    #pragma unroll
    for (int i = 0; i < 4; ++i) {
        const int ci = i * 512 + tid;
        arow[i] = ci >> 3;
        aoff[i] = ((ci & 7) ^ (arow[i] & 7)) * 8;
    }
    #pragma unroll
    for (int i = 0; i < 3; ++i) {
        const int ci = i * 512 + tid;
        brow[i] = ci >> 3;
        boff[i] = ((ci & 7) ^ (brow[i] & 7)) * 8;
    }
    const __bf16* Ab = A  + (size_t)bm0 * H_;
    const __bf16* Bb = Bt + (size_t)bn0 * H_;

    auto stage = [&](int buf, int kt1) {
        const int kb = kt1 * 64;
        #pragma unroll
        for (int i = 0; i < 4; ++i)
            async_cp16(Ab + (size_t)arow[i] * H_ + kb + aoff[i],
                       &Asl[buf][(i * 512 + wid * 64) * 8]);
        #pragma unroll
        for (int i = 0; i < 3; ++i)
            async_cp16(Bb + (size_t)brow[i] * H_ + kb + boff[i],
                       &Bsl[buf][(i * 512 + wid * 64) * 8]);
    };
    auto rdA = [&](int buf, int kh, int mi) -> bf16x8 {
        const int row = wr * 128 + mi * 16 + fr;
        const int kc  = kh * 4 + fq;
        return *(const bf16x8*)&Asl[buf][row * 64 + ((kc ^ (row & 7)) << 3)];
    };
    auto rdB = [&](int buf, int kh, int nj) -> bf16x8 {
        const int row = wc * 48 + nj * 16 + fr;
        const int kc  = kh * 4 + fq;
        return *(const bf16x8*)&Bsl[buf][row * 64 + ((kc ^ (row & 7)) << 3)];
    };

    f32x4 acc[8][3] = {};

    stage(0, 0);
    asm volatile("s_waitcnt vmcnt(0)");
    __builtin_amdgcn_sched_barrier(0);
    __builtin_amdgcn_s_barrier();

    const int NT = H_ / 64;
    for (int kt = 0; kt < NT; ++kt) {
        const int cur = kt & 1, nb = cur ^ 1;
        const bool pf = (kt + 1 < NT);
        bf16x8 af[8], bfr[3];

        #pragma unroll
        for (int mi = 0; mi < 8; ++mi) af[mi] = rdA(cur, 0, mi);
        #pragma unroll
        for (int nj = 0; nj < 3; ++nj) bfr[nj] = rdB(cur, 0, nj);
        if (pf) stage(nb, kt + 1);
        __builtin_amdgcn_s_barrier();
        asm volatile("s_waitcnt lgkmcnt(0)");
        __builtin_amdgcn_sched_barrier(0);
        __builtin_amdgcn_s_setprio(1);
        #pragma unroll
        for (int mi = 0; mi < 8; ++mi)
            #pragma unroll
            for (int nj = 0; nj < 3; ++nj)
                acc[mi][nj] = __builtin_amdgcn_mfma_f32_16x16x32_bf16(af[mi], bfr[nj], acc[mi][nj], 0, 0, 0);
        __builtin_amdgcn_s_setprio(0);
        __builtin_amdgcn_s_barrier();

        #pragma unroll
        for (int mi = 0; mi < 8; ++mi) af[mi] = rdA(cur, 1, mi);
        #pragma unroll
        for (int nj = 0; nj < 3; ++nj) bfr[nj] = rdB(cur, 1, nj);
        __builtin_amdgcn_s_barrier();
        asm volatile("s_waitcnt lgkmcnt(0)");
        __builtin_amdgcn_sched_barrier(0);
        __builtin_amdgcn_s_setprio(1);
        #pragma unroll
        for (int mi = 0; mi < 8; ++mi)
            #pragma unroll
            for (int nj = 0; nj < 3; ++nj)
                acc[mi][nj] = __builtin_amdgcn_mfma_f32_16x16x32_bf16(af[mi], bfr[nj], acc[mi][nj], 0, 0, 0);
        __builtin_amdgcn_s_setprio(0);
        asm volatile("s_waitcnt vmcnt(0)");
        __builtin_amdgcn_sched_barrier(0);
        __builtin_amdgcn_s_barrier();
    }

    const int colw = bn0 + wc * 48;
    bf16x8 aT[8][2], bW[3][2];
    #pragma unroll
    for (int mi = 0; mi < 8; ++mi)
        #pragma unroll
        for (int kh = 0; kh < 2; ++kh)
            aT[mi][kh] = *(const bf16x8*)&TMPo16[(size_t)(bm0 + wr * 128 + mi * 16 + fr) * 64 + kh * 32 + fq * 8];
    #pragma unroll
    for (int nj = 0; nj < 3; ++nj)
        #pragma unroll
        for (int kh = 0; kh < 2; ++kh)
            bW[nj][kh] = *(const bf16x8*)&WBo16[(size_t)(colw + nj * 16 + fr) * 64 + kh * 32 + fq * 8];
    #pragma unroll
    for (int mi = 0; mi < 8; ++mi)
        #pragma unroll
        for (int nj = 0; nj < 3; ++nj) {
            acc[mi][nj] = __builtin_amdgcn_mfma_f32_16x16x32_bf16(aT[mi][0], bW[nj][0], acc[mi][nj], 0, 0, 0);
            acc[mi][nj] = __builtin_amdgcn_mfma_f32_16x16x32_bf16(aT[mi][1], bW[nj][1], acc[mi][nj], 0, 0, 0);
        }
    #pragma unroll
    for (int mi = 0; mi < 8; ++mi)
        #pragma unroll
        for (int nj = 0; nj < 3; ++nj) {
            const int col = colw + nj * 16 + fr;
            if (col < Ntot) {
                #pragma unroll
                for (int rr = 0; rr < 4; ++rr) {
                    const int row = bm0 + wr * 128 + mi * 16 + fq * 4 + rr;
                    if (row < M) C[(size_t)row * H_ + col] = acc[mi][nj][rr];
                }
            }
        }
}

// ---------------------------------------------------------------- RoPE tables
__global__ void rope_table_kernel(float* __restrict__ cost, float* __restrict__ sint)
{
    const int p = blockIdx.x;
    const int i = threadIdx.x;
    const float inv = powf(10000.f, -(float)(2 * i) / (float)HD_);
    const float a = (float)p * inv;
    cost[p * 64 + i] = cosf(a);
    sint[p * 64 + i] = sinf(a);
}

// ---------------------------------------------------------------- rope16
__global__ __launch_bounds__(256)
void rope16_kernel(__bf16* __restrict__ q16, __bf16* __restrict__ k16,
                   const int* __restrict__ kv_lens,
                   const float* __restrict__ cost, const float* __restrict__ sint)
{
    const int r = blockIdx.x;
    int pos; bool dok;
    if (r < DOFF_) {
        if      (r < 1024) pos = r;
        else if (r < 1536) pos = r - 1024;
        else if (r < 2304) pos = r - 1536;
        else               pos = r - 2304;
        dok = true;
    } else {
        pos = kv_lens[r - DOFF_];
        dok = false;
    }
    const int tid = threadIdx.x;
    const int h = tid >> 3, sub = tid & 7;
    const int i0 = sub * 8;
    const size_t b1 = (size_t)r * H_ + h * HD_ + i0;
    const size_t b2 = b1 + 64;

    float cs[8], sn[8];
    #pragma unroll
    for (int j = 0; j < 8; ++j) { cs[j] = cost[pos * 64 + i0 + j]; sn[j] = sint[pos * 64 + i0 + j]; }

    {
        bf16x8 x1 = *(const bf16x8*)&q16[b1], x2 = *(const bf16x8*)&q16[b2];
        bf16x8 o1, o2;
        #pragma unroll
        for (int j = 0; j < 8; ++j) {
            const float f1 = (float)x1[j], f2 = (float)x2[j];
            o1[j] = (__bf16)(f1 * cs[j] - f2 * sn[j]);
            o2[j] = (__bf16)(f2 * cs[j] + f1 * sn[j]);
        }
        *(bf16x8*)&q16[b1] = o1; *(bf16x8*)&q16[b2] = o2;
    }
    if (dok) {
        bf16x8 x1 = *(const bf16x8*)&k16[b1], x2 = *(const bf16x8*)&k16[b2];
        bf16x8 o1, o2;
        #pragma unroll
        for (int j = 0; j < 8; ++j) {
            const float f1 = (float)x1[j], f2 = (float)x2[j];
            o1[j] = (__bf16)(f1 * cs[j] - f2 * sn[j]);
            o2[j] = (__bf16)(f2 * cs[j] + f1 * sn[j]);
        }
        *(bf16x8*)&k16[b1] = o1; *(bf16x8*)&k16[b2] = o2;
    }
}

// ---------------------------------------------------------------- V transpose per head (bf16 in)
__global__ __launch_bounds__(256)
void transpose_v_kernel(const __bf16* __restrict__ v16, __bf16* __restrict__ vT)
{
    __shared__ __bf16 s[64][136];
    const int tb = blockIdx.x;
    const int h  = blockIdx.y;
    const int tid = threadIdx.x;
    #pragma unroll
    for (int i = 0; i < 4; ++i) {
        const int idx = i * 256 + tid;
        const int row = idx >> 4;
        const int c8  = (idx & 15) * 8;
        *(bf16x8*)&s[row][c8] = *(const bf16x8*)&v16[(size_t)(tb * 64 + row) * H_ + h * HD_ + c8];
    }
    __syncthreads();
    #pragma unroll
    for (int i = 0; i < 4; ++i) {
        const int idx = i * 256 + tid;
        const int d = idx >> 3;
        const int c = idx & 7;
        bf16x8 w;
        #pragma unroll
        for (int j = 0; j < 8; ++j) w[j] = s[c * 8 + j][d];
        *(bf16x8*)&vT[(size_t)(h * HD_ + d) * T_ + tb * 64 + c * 8] = w;
    }
}

// ---------------------------------------------------------------- prefill attention (MFMA bf16, flash, K/V dbuf, LPT order)
__global__ __launch_bounds__(256)
void prefill_attn_mfma(const __bf16* __restrict__ q16, const __bf16* __restrict__ k16,
                       const __bf16* __restrict__ vT, __bf16* __restrict__ attn16)
{
    const int qb = QBORD_[blockIdx.x];   // heavy-first permutation
    int soff, qoff;
    if      (qb < 16) { soff = 0;    qoff = qb * 64; }
    else if (qb < 24) { soff = 1024; qoff = (qb - 16) * 64; }
    else if (qb < 36) { soff = 1536; qoff = (qb - 24) * 64; }
    else              { soff = 2304; qoff = (qb - 36) * 64; }
    const int h = blockIdx.y;

    __shared__ __align__(16) __bf16 Kl[2][64 * 128];
    __shared__ __align__(16) __bf16 Vl[2][128 * 64];
    __shared__ __align__(16) __bf16 Pl[4][16 * 64];

    const int tid = threadIdx.x, lane = tid & 63, wid = tid >> 6;
    const int fr = lane & 15, fq = lane >> 4;

    const int grow0 = soff + qoff + wid * 16;
    bf16x8 qf[4];
    #pragma unroll
    for (int ks = 0; ks < 4; ++ks)
        qf[ks] = *(const bf16x8*)&q16[(size_t)(grow0 + fr) * H_ + h * HD_ + ks * 32 + fq * 8];

    auto stageK = [&](int buf, int t) {
        const int kt = t * 64;
        #pragma unroll
        for (int i = 0; i < 4; ++i) {
            const int chunk = i * 256 + tid;
            const int row = chunk >> 4, c = chunk & 15;
            async_cp16(k16 + (size_t)(soff + kt + row) * H_ + h * HD_ + ((c ^ (row & 7)) * 8),
                       Kl[buf] + (size_t)(i * 256 + wid * 64) * 8);
        }
    };
    auto stageV = [&](int buf, int t) {
        const int kt = t * 64;
        #pragma unroll
        for (int i = 0; i < 4; ++i) {
            const int chunk = i * 256 + tid;
            const int row = chunk >> 3, c = chunk & 7;
            async_cp16(vT + (size_t)(h * HD_ + row) * T_ + soff + kt + ((c ^ (row & 7)) * 8),
                       Vl[buf] + (size_t)(i * 256 + wid * 64) * 8);
        }
    };

    float m[4], l[4];
    #pragma unroll
    for (int r = 0; r < 4; ++r) { m[r] = -1e30f; l[r] = 0.f; }
    f32x4 o[8] = {};

    const int ntiles = qoff / 64 + 1;
    stageK(0, 0); stageV(0, 0);
    if (ntiles > 1) {
        stageK(1, 1); stageV(1, 1);
        asm volatile("s_waitcnt vmcnt(8)");
    } else {
        asm volatile("s_waitcnt vmcnt(0)");
    }
    __builtin_amdgcn_sched_barrier(0);
    __builtin_amdgcn_s_barrier();

    for (int t = 0; t < ntiles; ++t) {
        const int b = t & 1;
        const int kt = t * 64;

        f32x4 s[4] = {};
        __builtin_amdgcn_s_setprio(1);
        #pragma unroll
        for (int sub = 0; sub < 4; ++sub)
            #pragma unroll
            for (int ks = 0; ks < 4; ++ks) {
                bf16x8 bk = *(const bf16x8*)&Kl[b][(sub * 16 + fr) * 128 + (((ks * 4 + fq) ^ (fr & 7)) * 8)];
                s[sub] = __builtin_amdgcn_mfma_f32_16x16x32_bf16(qf[ks], bk, s[sub], 0, 0, 0);
            }
        __builtin_amdgcn_s_setprio(0);

        float p[4][4];
        #pragma unroll
        for (int sub = 0; sub < 4; ++sub)
            #pragma unroll
            for (int r = 0; r < 4; ++r) {
                const int qpos = qoff + wid * 16 + fq * 4 + r;
                const int kpos = kt + sub * 16 + fr;
                p[sub][r] = (kpos <= qpos) ? s[sub][r] * SCALE_ : -1e30f;
            }
        float tm2[4];
        #pragma unroll
        for (int r = 0; r < 4; ++r) {
            float tm = fmaxf(fmaxf(p[0][r], p[1][r]), fmaxf(p[2][r], p[3][r]));
            tm = fmaxf(tm, __shfl_xor(tm, 1));
            tm = fmaxf(tm, __shfl_xor(tm, 2));
            tm = fmaxf(tm, __shfl_xor(tm, 4));
            tm = fmaxf(tm, __shfl_xor(tm, 8));
            tm2[r] = tm;
        }
        bool need = false;
        #pragma unroll
        for (int r = 0; r < 4; ++r) need |= (tm2[r] > m[r] + 8.f);
        if (__any(need)) {
            #pragma unroll
            for (int r = 0; r < 4; ++r) {
                const float mn = fmaxf(m[r], tm2[r]);
                const float f  = __expf(m[r] - mn);
                m[r] = mn;
                l[r] *= f;
                #pragma unroll
                for (int c = 0; c < 8; ++c) o[c][r] *= f;
            }
        }
        #pragma unroll
        for (int r = 0; r < 4; ++r) {
            float ls = 0.f;
            #pragma unroll
            for (int sub = 0; sub < 4; ++sub) {
                p[sub][r] = __expf(p[sub][r] - m[r]);
                ls += p[sub][r];
            }
            l[r] += ls;
        }

        #pragma unroll
        for (int sub = 0; sub < 4; ++sub)
            #pragma unroll
            for (int r = 0; r < 4; ++r) {
                const int qr = fq * 4 + r;
                Pl[wid][qr * 64 + ((sub * 16 + fr) ^ ((qr & 7) << 3))] = (__bf16)p[sub][r];
            }
        bf16x8 pa[2];
        #pragma unroll
        for (int a = 0; a < 2; ++a)
            pa[a] = *(const bf16x8*)&Pl[wid][fr * 64 + (((a * 4 + fq) ^ (fr & 7)) * 8)];

        __builtin_amdgcn_s_setprio(1);
        #pragma unroll
        for (int a = 0; a < 2; ++a)
            #pragma unroll
            for (int c = 0; c < 8; ++c) {
                bf16x8 bv = *(const bf16x8*)&Vl[b][(c * 16 + fr) * 64 + (((a * 4 + fq) ^ (fr & 7)) * 8)];
                o[c] = __builtin_amdgcn_mfma_f32_16x16x32_bf16(pa[a], bv, o[c], 0, 0, 0);
            }
        __builtin_amdgcn_s_setprio(0);

        __builtin_amdgcn_s_barrier();
        __builtin_amdgcn_sched_barrier(0);
        if (t + 2 < ntiles) { stageK(b, t + 2); stageV(b, t + 2); }
        if (t + 1 < ntiles) {
            if (t + 2 < ntiles) asm volatile("s_waitcnt vmcnt(8)");
            else                asm volatile("s_waitcnt vmcnt(0)");
            __builtin_amdgcn_sched_barrier(0);
            __builtin_amdgcn_s_barrier();
        }
    }

    float inv[4];
    #pragma unroll
    for (int r = 0; r < 4; ++r) {
        float ls = l[r];
        ls += __shfl_xor(ls, 1); ls += __shfl_xor(ls, 2);
        ls += __shfl_xor(ls, 4); ls += __shfl_xor(ls, 8);
        inv[r] = 1.f / ls;
    }
    #pragma unroll
    for (int c = 0; c < 8; ++c)
        #pragma unroll
        for (int r = 0; r < 4; ++r)
            attn16[(size_t)(grow0 + fq * 4 + r) * H_ + h * HD_ + c * 16 + fr] = (__bf16)(o[c][r] * inv[r]);
}

// ---------------------------------------------------------------- decode attention
__global__ __launch_bounds__(256)
void decode_attn_kernel(const __bf16* __restrict__ q16, const __bf16* __restrict__ k16,
                        const __bf16* __restrict__ v16, const float* __restrict__ kc,
                        const float* __restrict__ vc, const int* __restrict__ kv_lens,
                        const float* __restrict__ cost, const float* __restrict__ sint,
                        __bf16* __restrict__ attn16)
{
    const int b = blockIdx.x, h = blockIdx.y;
    const int kvlen = kv_lens[b];
    const int L = kvlen + 1;
    const int tid = threadIdx.x, lane = tid & 63, w = tid >> 6;

    __shared__ float sc_s[LMAX_];
    __shared__ float red[4];
    __shared__ float oacc[HD_];

    const __bf16* qrow = q16 + (size_t)(DOFF_ + b) * H_ + h * HD_;
    const float q1 = (float)qrow[lane], q2 = (float)qrow[lane + 64];
    const __bf16* kdrow = k16 + (size_t)(DOFF_ + b) * H_ + h * HD_;

    for (int l = w; l < L; l += 4) {
        float k1, k2;
        if (l == kvlen) { k1 = (float)kdrow[lane]; k2 = (float)kdrow[lane + 64]; }
        else {
            const float* src = kc + (((size_t)b * LMAX_ + l) * NH_ + h) * HD_;
            k1 = src[lane]; k2 = src[lane + 64];
        }
        const float c = cost[l * 64 + lane], s = sint[l * 64 + lane];
        float d = q1 * (k1 * c - k2 * s) + q2 * (k2 * c + k1 * s);
        #pragma unroll
        for (int off = 1; off < 64; off <<= 1) d += __shfl_xor(d, off);
        if (lane == 0) sc_s[l] = d * SCALE_;
    }
    __syncthreads();

    float mx = -1e30f;
    for (int i = tid; i < L; i += 256) mx = fmaxf(mx, sc_s[i]);
    #pragma unroll
    for (int off = 1; off < 64; off <<= 1) mx = fmaxf(mx, __shfl_xor(mx, off));
    if (lane == 0) red[w] = mx;
    __syncthreads();
    mx = fmaxf(fmaxf(red[0], red[1]), fmaxf(red[2], red[3]));
    __syncthreads();

    float sum = 0.f;
    for (int i = tid; i < L; i += 256) { const float e = __expf(sc_s[i] - mx); sc_s[i] = e; sum += e; }
    #pragma unroll
    for (int off = 1; off < 64; off <<= 1) sum += __shfl_xor(sum, off);
    if (lane == 0) red[w] = sum;
    __syncthreads();
    sum = red[0] + red[1] + red[2] + red[3];
    const float inv = 1.f / sum;

    const int d = tid & 127, team = tid >> 7;
    const __bf16* vdrow = v16 + (size_t)(DOFF_ + b) * H_ + h * HD_;
    float acc = 0.f;
    for (int l = team; l < L; l += 2) {
        float vv;
        if (l == kvlen) vv = (float)vdrow[d];
        else            vv = vc[(((size_t)b * LMAX_ + l) * NH_ + h) * HD_ + d];
        acc += sc_s[l] * vv;
    }
    if (team == 1) oacc[d] = acc;
    __syncthreads();
    if (team == 0) attn16[(size_t)(DOFF_ + b) * H_ + h * HD_ + d] = (__bf16)((acc + oacc[d]) * inv);
}

// ---------------------------------------------------------------- host launch
extern "C" void kernel_launch(void* const* d_in, const int* in_sizes, int n_in,
                              void* d_out, int out_size, void* d_ws, size_t ws_size,
                              hipStream_t stream)
{
    const float* hs     = (const float*)d_in[0];
    const float* wq     = (const float*)d_in[1];
    const float* wk     = (const float*)d_in[2];
    const float* wv     = (const float*)d_in[3];
    const float* wo     = (const float*)d_in[4];
    const float* la_q   = (const float*)d_in[5];
    const float* lb_q   = (const float*)d_in[6];
    const float* la_k   = (const float*)d_in[7];
    const float* lb_k   = (const float*)d_in[8];
    const float* la_v   = (const float*)d_in[9];
    const float* lb_v   = (const float*)d_in[10];
    const float* la_o   = (const float*)d_in[11];
    const float* lb_o   = (const float*)d_in[12];
    const float* kcache = (const float*)d_in[13];
    const float* vcache = (const float*)d_in[14];
    const int*   kvlen  = (const int*)d_in[15];
    float* out = (float*)d_out;

    float*  costab = (float*)d_ws;
    float*  sintab = costab + 1024 * 64;
    __bf16* TMP16  = (__bf16*)(sintab + 1024 * 64);       // [3][MPAD][64]
    __bf16* TMPo16 = TMP16 + (size_t)3 * MPAD_ * 64;      // [MPAD][64]
    __bf16* WB16   = TMPo16 + (size_t)MPAD_ * 64;         // [12288][64]
    __bf16* WBo16  = WB16 + (size_t)3 * H_ * 64;          // [4352][64]
    __bf16* q16    = WBo16 + (size_t)4352 * 64;           // [T][H]
    __bf16* k16    = q16 + (size_t)T_ * H_;
    __bf16* v16    = k16 + (size_t)T_ * H_;
    __bf16* hsb    = v16 + (size_t)T_ * H_;               // [MPAD][H]: hs bf16, later attn16
    __bf16* wT     = hsb + (size_t)MPAD_ * H_;            // [3][H][H]
    __bf16* vT     = wT + (size_t)H_ * H_;                // reuse wk^T slot after QKV GEMM
    __bf16* attn16 = hsb;

    rope_table_kernel<<<dim3(1024), dim3(64), 0, stream>>>(costab, sintab);
    hs_prep_kernel<<<dim3(T_), dim3(256), 0, stream>>>(hs, hsb, la_q, la_k, la_v, TMP16);
    transpose_bf16_kernel<<<dim3(64, 64, 3), dim3(256), 0, stream>>>(
        wq, wk, wv, wT, wT + (size_t)H_ * H_, wT + (size_t)2 * H_ * H_);
    wb_build_kernel<<<dim3(4, 16), dim3(256), 0, stream>>>(lb_q, lb_k, lb_v, lb_o, WB16, WBo16);
    gemm_qkv<<<dim3(21, 48), dim3(512), 0, stream>>>(
        hsb, wT, TMP16, WB16, q16, k16, v16, T_);
    rope16_kernel<<<dim3(T_), dim3(256), 0, stream>>>(q16, k16, kvlen, costab, sintab);
    transpose_v_kernel<<<dim3(40, 32), dim3(256), 0, stream>>>(v16, vT);
    prefill_attn_mfma<<<dim3(40, 32), dim3(256), 0, stream>>>(q16, k16, vT, attn16);
    decode_attn_kernel<<<dim3(DEC_, NH_), dim3(256), 0, stream>>>(q16, k16, v16, kcache, vcache,
                                                                  kvlen, costab, sintab, attn16);
    transpose_bf16_kernel<<<dim3(64, 64, 1), dim3(256), 0, stream>>>(wo, wo, wo, wT, wT, wT);
    lora_tmp_bf16_kernel<<<dim3(T_), dim3(256), 0, stream>>>(attn16, la_o, TMPo16);
    gemm_out<<<dim3(11, 22), dim3(512), 0, stream>>>(
        attn16, wT, TMPo16, WBo16, out, T_, H_);
}